// Round 1
// baseline (1470.981 us; speedup 1.0000x reference)
//
#include <hip/hip_runtime.h>
#include <hip/hip_bf16.h>

#define NL 6
#define DM 768
#define DI 1536
#define DS 16
#define NRANK 48
#define DBC 80
#define BATCH 2
#define SEQ 1024
#define NTOK (BATCH*SEQ)
#define NCHUNK 16
#define CHLEN 64

typedef __attribute__((ext_vector_type(8))) short short8;
typedef __attribute__((ext_vector_type(4))) float f32x4;

__device__ inline unsigned short f2bf(float f) {
  union { float f; unsigned u; } x; x.f = f;
  unsigned r = x.u + 0x7FFF + ((x.u >> 16) & 1);
  return (unsigned short)(r >> 16);
}

// C[M,N] = A[M,K] * W[N,K]^T  (A row-major lda, W row-major ldw), fp32 in, bf16 MFMA, fp32 out.
// EPI 0: plain store. EPI 1: softplus(v + bias[col]). EPI 2: v + resid[row*ldc+col].
template<int EPI>
__global__ __launch_bounds__(256) void gemm_bt_k(
    const float* __restrict__ A, int lda,
    const float* __restrict__ W, int ldw,
    float* __restrict__ C, int ldc,
    int M, int N, int K,
    const float* __restrict__ bias,
    const float* __restrict__ resid) {
  __shared__ unsigned short As[64][40];
  __shared__ unsigned short Ws[64][40];
  const int tid = threadIdx.x;
  const int bm = blockIdx.y * 64;
  const int bn = blockIdx.x * 64;
  const int srow = tid >> 2;
  const int scol = (tid & 3) * 8;
  const int lane = tid & 63;
  const int wv = tid >> 6;
  const int wm = (wv >> 1) * 32;
  const int wn = (wv & 1) * 32;
  const int fr = lane & 15;
  const int fk = (lane >> 4) * 8;

  f32x4 acc[2][2];
#pragma unroll
  for (int i = 0; i < 2; i++)
#pragma unroll
    for (int j = 0; j < 2; j++) acc[i][j] = (f32x4){0.f, 0.f, 0.f, 0.f};

  const int nk = (K + 31) / 32;
  for (int kk = 0; kk < nk; kk++) {
    const int k0 = kk * 32;
    // stage A tile (64 x 32) fp32 -> bf16
    {
      const float* src = A + (size_t)(bm + srow) * lda + k0 + scol;
      unsigned short tmp[8];
      if (k0 + scol + 8 <= K) {
#pragma unroll
        for (int j = 0; j < 8; j++) tmp[j] = f2bf(src[j]);
      } else {
#pragma unroll
        for (int j = 0; j < 8; j++) tmp[j] = (k0 + scol + j < K) ? f2bf(src[j]) : (unsigned short)0;
      }
#pragma unroll
      for (int j = 0; j < 8; j++) As[srow][scol + j] = tmp[j];
    }
    // stage W tile (64 x 32)
    {
      const bool ok = (bn + srow) < N;
      const float* src = W + (size_t)(bn + srow) * ldw + k0 + scol;
      unsigned short tmp[8];
      if (ok && (k0 + scol + 8 <= K)) {
#pragma unroll
        for (int j = 0; j < 8; j++) tmp[j] = f2bf(src[j]);
      } else {
#pragma unroll
        for (int j = 0; j < 8; j++) tmp[j] = (ok && (k0 + scol + j < K)) ? f2bf(src[j]) : (unsigned short)0;
      }
#pragma unroll
      for (int j = 0; j < 8; j++) Ws[srow][scol + j] = tmp[j];
    }
    __syncthreads();

    short8 a0 = *(const short8*)&As[wm + fr][fk];
    short8 a1 = *(const short8*)&As[wm + 16 + fr][fk];
    short8 b0 = *(const short8*)&Ws[wn + fr][fk];
    short8 b1 = *(const short8*)&Ws[wn + 16 + fr][fk];
    acc[0][0] = __builtin_amdgcn_mfma_f32_16x16x32_bf16(a0, b0, acc[0][0], 0, 0, 0);
    acc[0][1] = __builtin_amdgcn_mfma_f32_16x16x32_bf16(a0, b1, acc[0][1], 0, 0, 0);
    acc[1][0] = __builtin_amdgcn_mfma_f32_16x16x32_bf16(a1, b0, acc[1][0], 0, 0, 0);
    acc[1][1] = __builtin_amdgcn_mfma_f32_16x16x32_bf16(a1, b1, acc[1][1], 0, 0, 0);
    __syncthreads();
  }

#pragma unroll
  for (int i = 0; i < 2; i++) {
#pragma unroll
    for (int j = 0; j < 2; j++) {
#pragma unroll
      for (int r = 0; r < 4; r++) {
        int row = bm + wm + i * 16 + (lane >> 4) * 4 + r;
        int col = bn + wn + j * 16 + fr;
        if (col < N) {
          float v = acc[i][j][r];
          if (EPI == 1) {
            float xv = v + bias[col];
            v = (xv > 20.f) ? xv : log1pf(__expf(xv));
          }
          if (EPI == 2) {
            v += resid[(size_t)row * ldc + col];
          }
          C[(size_t)row * ldc + col] = v;
        }
      }
    }
  }
}

// depthwise causal conv(4) + bias + silu. reads xc half of xz, writes xc buffer.
__global__ __launch_bounds__(256) void conv_silu_k(const float* __restrict__ xz,
                                                   const float* __restrict__ cw,
                                                   const float* __restrict__ cb,
                                                   float* __restrict__ xc) {
  int idx = blockIdx.x * 256 + threadIdx.x;  // NTOK*DI
  int d = idx % DI;
  int m = idx / DI;
  int l = m % SEQ;
  float s = cb[d];
#pragma unroll
  for (int j = 0; j < 4; j++) {
    int tl = l - 3 + j;
    if (tl >= 0) s += xz[(size_t)(m - 3 + j) * (2 * DI) + d] * cw[d * 4 + j];
  }
  float sig = 1.f / (1.f + __expf(-s));
  xc[idx] = s * sig;
}

// chunked scan pass 1: per (b,d,chunk) compute prod(dA) and local h (h_in = 0)
__global__ __launch_bounds__(256) void scan1_k(const float* __restrict__ dt,
                                               const float* __restrict__ xc,
                                               const float* __restrict__ dbc,
                                               const float* __restrict__ A_log_l,
                                               float* __restrict__ cumA,
                                               float* __restrict__ hloc) {
  const int tid = threadIdx.x;
  const int j = blockIdx.x;          // chunk
  const int cg = blockIdx.y;         // 0..11
  const int b = cg / 6;
  const int d = (cg % 6) * 256 + tid;
  const int c = b * DI + d;

  float Av[DS];
  const float* al = A_log_l + (size_t)d * DS;
#pragma unroll
  for (int s = 0; s < DS; s++) Av[s] = -__expf(al[s]);

  float ap[DS], h[DS];
#pragma unroll
  for (int s = 0; s < DS; s++) { ap[s] = 1.f; h[s] = 0.f; }

  const int t0 = j * CHLEN;
  for (int t = 0; t < CHLEN; t++) {
    int m = b * SEQ + t0 + t;
    float dtv = dt[(size_t)m * DI + d];
    float xv = xc[(size_t)m * DI + d];
    float dtx = dtv * xv;
    const float* bp = dbc + (size_t)m * DBC + NRANK;
#pragma unroll
    for (int s = 0; s < DS; s++) {
      float dA = __expf(dtv * Av[s]);
      h[s] = fmaf(dA, h[s], dtx * bp[s]);
      ap[s] *= dA;
    }
  }
  size_t base = ((size_t)j * (BATCH * DI) + c) * DS;
#pragma unroll
  for (int q = 0; q < 4; q++) {
    *(f32x4*)&cumA[base + q * 4] = (f32x4){ap[q*4], ap[q*4+1], ap[q*4+2], ap[q*4+3]};
    *(f32x4*)&hloc[base + q * 4] = (f32x4){h[q*4], h[q*4+1], h[q*4+2], h[q*4+3]};
  }
}

// pass 2: sequential combine over chunks; emit h_in per chunk and final state
__global__ __launch_bounds__(256) void scan2_k(const float* __restrict__ cumA,
                                               const float* __restrict__ hloc,
                                               float* __restrict__ hin,
                                               float* __restrict__ states_out) {
  int idx = blockIdx.x * 256 + threadIdx.x;  // BATCH*DI*DS = 49152
  const int stride = BATCH * DI * DS;
  float h = 0.f;
  for (int j = 0; j < NCHUNK; j++) {
    hin[(size_t)j * stride + idx] = h;
    h = fmaf(cumA[(size_t)j * stride + idx], h, hloc[(size_t)j * stride + idx]);
  }
  states_out[idx] = h;
}

// pass 3: rerun scan with true h_in, produce y_final = (y + D*xc)*silu(z)
__global__ __launch_bounds__(256) void scan3_k(const float* __restrict__ dt,
                                               const float* __restrict__ xc,
                                               const float* __restrict__ dbc,
                                               const float* __restrict__ xz,
                                               const float* __restrict__ A_log_l,
                                               const float* __restrict__ Dsk,
                                               const float* __restrict__ hin,
                                               float* __restrict__ y) {
  const int tid = threadIdx.x;
  const int j = blockIdx.x;
  const int cg = blockIdx.y;
  const int b = cg / 6;
  const int d = (cg % 6) * 256 + tid;
  const int c = b * DI + d;

  float Av[DS];
  const float* al = A_log_l + (size_t)d * DS;
#pragma unroll
  for (int s = 0; s < DS; s++) Av[s] = -__expf(al[s]);

  float h[DS];
  size_t base = ((size_t)j * (BATCH * DI) + c) * DS;
#pragma unroll
  for (int s = 0; s < DS; s++) h[s] = hin[base + s];

  float dval = Dsk[d];
  const int t0 = j * CHLEN;
  for (int t = 0; t < CHLEN; t++) {
    int m = b * SEQ + t0 + t;
    float dtv = dt[(size_t)m * DI + d];
    float xv = xc[(size_t)m * DI + d];
    float dtx = dtv * xv;
    const float* bp = dbc + (size_t)m * DBC + NRANK;
    const float* cp = bp + DS;
    float ysum = 0.f;
#pragma unroll
    for (int s = 0; s < DS; s++) {
      float dA = __expf(dtv * Av[s]);
      h[s] = fmaf(dA, h[s], dtx * bp[s]);
      ysum = fmaf(h[s], cp[s], ysum);
    }
    float zv = xz[(size_t)m * (2 * DI) + DI + d];
    float sig = 1.f / (1.f + __expf(-zv));
    y[(size_t)m * DI + d] = (ysum + dval * xv) * (zv * sig);
  }
}

// LN (w,b) then optionally LN_noaffine + adaln modulate. One block per token row.
template<bool ADA>
__global__ __launch_bounds__(256) void ln_k(const float* __restrict__ in,
                                            const float* __restrict__ w,
                                            const float* __restrict__ bb,
                                            const float* __restrict__ ss,
                                            float* __restrict__ out) {
  __shared__ float red[8];
  const int row = blockIdx.x;
  const int bt = row / SEQ;
  const int tid = threadIdx.x;
  const float* x = in + (size_t)row * DM;
  float v[3];
#pragma unroll
  for (int i = 0; i < 3; i++) v[i] = x[tid + i * 256];
  float s1 = v[0] + v[1] + v[2];
  float s2 = v[0]*v[0] + v[1]*v[1] + v[2]*v[2];
#pragma unroll
  for (int o = 32; o > 0; o >>= 1) { s1 += __shfl_down(s1, o); s2 += __shfl_down(s2, o); }
  int wv = tid >> 6, ln = tid & 63;
  if (ln == 0) { red[wv*2] = s1; red[wv*2+1] = s2; }
  __syncthreads();
  s1 = red[0] + red[2] + red[4] + red[6];
  s2 = red[1] + red[3] + red[5] + red[7];
  float mu = s1 * (1.f / DM);
  float var = s2 * (1.f / DM) - mu * mu;
  float rs = rsqrtf(var + 1e-5f);
  float t[3];
#pragma unroll
  for (int i = 0; i < 3; i++) {
    int c = tid + i * 256;
    t[i] = (v[i] - mu) * rs * w[c] + bb[c];
  }
  if (!ADA) {
#pragma unroll
    for (int i = 0; i < 3; i++) out[(size_t)row * DM + tid + i * 256] = t[i];
    return;
  }
  __syncthreads();
  s1 = t[0] + t[1] + t[2];
  s2 = t[0]*t[0] + t[1]*t[1] + t[2]*t[2];
#pragma unroll
  for (int o = 32; o > 0; o >>= 1) { s1 += __shfl_down(s1, o); s2 += __shfl_down(s2, o); }
  if (ln == 0) { red[wv*2] = s1; red[wv*2+1] = s2; }
  __syncthreads();
  s1 = red[0] + red[2] + red[4] + red[6];
  s2 = red[1] + red[3] + red[5] + red[7];
  float mu2 = s1 * (1.f / DM);
  float var2 = s2 * (1.f / DM) - mu2 * mu2;
  float rs2 = rsqrtf(var2 + 1e-5f);
#pragma unroll
  for (int i = 0; i < 3; i++) {
    int c = tid + i * 256;
    float sc = ss[bt * (2 * DM) + c];
    float sh = ss[bt * (2 * DM) + DM + c];
    out[(size_t)row * DM + c] = (t[i] - mu2) * rs2 * (1.f + sc) + sh;
  }
}

// precompute adaln ss[l][b][e] = cond[b] . adaln_w[l][e] + adaln_b[l][e]
__global__ __launch_bounds__(256) void adaln_pre_k(const float* __restrict__ cond,
                                                   const float* __restrict__ aw,
                                                   const float* __restrict__ ab,
                                                   float* __restrict__ ss) {
  int idx = blockIdx.x * 256 + threadIdx.x;  // NL*BATCH*2*DM = 18432
  int e = idx % (2 * DM);
  int b = (idx / (2 * DM)) % BATCH;
  int l = idx / (BATCH * 2 * DM);
  const float* c = cond + b * 128;
  const float* wp = aw + ((size_t)l * (2 * DM) + e) * 128;
  float s = ab[l * (2 * DM) + e];
  for (int k = 0; k < 128; k++) s = fmaf(c[k], wp[k], s);
  ss[idx] = s;
}

extern "C" void kernel_launch(void* const* d_in, const int* in_sizes, int n_in,
                              void* d_out, int out_size, void* d_ws, size_t ws_size,
                              hipStream_t stream) {
  const float* x      = (const float*)d_in[0];
  const float* cond   = (const float*)d_in[1];
  const float* in_w   = (const float*)d_in[2];
  const float* conv_w = (const float*)d_in[3];
  const float* conv_b = (const float*)d_in[4];
  const float* xp_w   = (const float*)d_in[5];
  const float* dtp_w  = (const float*)d_in[6];
  const float* dtp_b  = (const float*)d_in[7];
  const float* A_log  = (const float*)d_in[8];
  const float* Dsk    = (const float*)d_in[9];
  const float* out_w  = (const float*)d_in[10];
  const float* norm_w = (const float*)d_in[11];
  const float* norm_b = (const float*)d_in[12];
  const float* ada_w  = (const float*)d_in[13];
  const float* ada_b  = (const float*)d_in[14];
  const float* fn_w   = (const float*)d_in[15];
  const float* fn_b   = (const float*)d_in[16];

  float* out_h = (float*)d_out;
  float* out_states = out_h + (size_t)NTOK * DM;

  float* p = (float*)d_ws;
  float* h_cur = p; p += (size_t)NTOK * DM;
  float* xz    = p; p += (size_t)NTOK * 2 * DI;
  float* xc    = p; p += (size_t)NTOK * DI;
  float* dbc   = p; p += (size_t)NTOK * DBC;
  float* dtb   = p; p += (size_t)NTOK * DI;
  float* yb    = p; p += (size_t)NTOK * DI;
  float* res2  = p; p += (size_t)NTOK * DM;
  float* cumA  = p; p += (size_t)NCHUNK * BATCH * DI * DS;
  float* hloc  = p; p += (size_t)NCHUNK * BATCH * DI * DS;
  float* hin   = p; p += (size_t)NCHUNK * BATCH * DI * DS;
  float* ss    = p; p += (size_t)NL * BATCH * 2 * DM;

  hipMemcpyAsync(h_cur, x, (size_t)NTOK * DM * sizeof(float),
                 hipMemcpyDeviceToDevice, stream);
  adaln_pre_k<<<72, 256, 0, stream>>>(cond, ada_w, ada_b, ss);

  for (int l = 0; l < NL; l++) {
    // in_proj: (2048x768) x (3072x768)^T -> xz
    gemm_bt_k<0><<<dim3(48, 32), 256, 0, stream>>>(
        h_cur, DM, in_w + (size_t)l * 2 * DI * DM, DM, xz, 2 * DI,
        NTOK, 2 * DI, DM, nullptr, nullptr);
    // conv + silu
    conv_silu_k<<<(NTOK * DI) / 256, 256, 0, stream>>>(
        xz, conv_w + (size_t)l * DI * 4, conv_b + (size_t)l * DI, xc);
    // x_proj: (2048x1536) x (80x1536)^T -> dbc
    gemm_bt_k<0><<<dim3(2, 32), 256, 0, stream>>>(
        xc, DI, xp_w + (size_t)l * DBC * DI, DI, dbc, DBC,
        NTOK, DBC, DI, nullptr, nullptr);
    // dt_proj + softplus: (2048x48) x (1536x48)^T -> dt
    gemm_bt_k<1><<<dim3(24, 32), 256, 0, stream>>>(
        dbc, DBC, dtp_w + (size_t)l * DI * NRANK, NRANK, dtb, DI,
        NTOK, DI, NRANK, dtp_b + (size_t)l * DI, nullptr);
    // chunked scan
    scan1_k<<<dim3(NCHUNK, 12), 256, 0, stream>>>(
        dtb, xc, dbc, A_log + (size_t)l * DI * DS, cumA, hloc);
    scan2_k<<<192, 256, 0, stream>>>(
        cumA, hloc, hin, out_states + (size_t)l * BATCH * DI * DS);
    scan3_k<<<dim3(NCHUNK, 12), 256, 0, stream>>>(
        dtb, xc, dbc, xz, A_log + (size_t)l * DI * DS, Dsk + (size_t)l * DI,
        hin, yb);
    // out_proj + residual: (2048x1536) x (768x1536)^T -> res2
    gemm_bt_k<2><<<dim3(12, 32), 256, 0, stream>>>(
        yb, DI, out_w + (size_t)l * DM * DI, DI, res2, DM,
        NTOK, DM, DI, nullptr, h_cur);
    // LN + adaln modulate -> h_cur
    ln_k<true><<<NTOK, 256, 0, stream>>>(
        res2, norm_w + (size_t)l * DM, norm_b + (size_t)l * DM,
        ss + (size_t)l * BATCH * 2 * DM, h_cur);
  }
  ln_k<false><<<NTOK, 256, 0, stream>>>(h_cur, fn_w, fn_b, nullptr, out_h);
}

// Round 2
// 1353.213 us; speedup vs baseline: 1.0870x; 1.0870x over previous
//
#include <hip/hip_runtime.h>
#include <hip/hip_bf16.h>

#define NL 6
#define DM 768
#define DI 1536
#define DS 16
#define NRANK 48
#define DBC 80
#define BATCH 2
#define SEQ 1024
#define NTOK (BATCH*SEQ)
#define NCHUNK 16
#define CHLEN 64

typedef __attribute__((ext_vector_type(8))) short short8;
typedef __attribute__((ext_vector_type(4))) float f32x4;

__device__ inline unsigned short f2bf(float f) {
  union { float f; unsigned u; } x; x.f = f;
  unsigned r = x.u + 0x7FFF + ((x.u >> 16) & 1);
  return (unsigned short)(r >> 16);
}

__device__ inline short8 cvt8(f32x4 a, f32x4 b) {
  union { short8 s; __hip_bfloat162 h[4]; } u;
  float2 p;
  p.x = a[0]; p.y = a[1]; u.h[0] = __float22bfloat162_rn(p);
  p.x = a[2]; p.y = a[3]; u.h[1] = __float22bfloat162_rn(p);
  p.x = b[0]; p.y = b[1]; u.h[2] = __float22bfloat162_rn(p);
  p.x = b[2]; p.y = b[3]; u.h[3] = __float22bfloat162_rn(p);
  return u.s;
}

// ---------------------------------------------------------------------------
// 128x128-tile bf16 MFMA GEMM, fp32 in (converted in staging), fp32 out.
// C[M,N] = A[M,K] * W[N,K]^T. Requires M%128==0, N%128==0, K%32==0.
// EPI 0: plain store. EPI 2: v + resid[row*ldc+col].
// Reg-staged (global->reg->cvt->ds_write), XOR slot-swizzled LDS,
// next-tile loads issued before MFMA cluster (overlap).
// ---------------------------------------------------------------------------
template<int EPI>
__global__ __launch_bounds__(256) void bt128_k(
    const float* __restrict__ A, int lda,
    const float* __restrict__ W, int ldw,
    float* __restrict__ C, int ldc,
    int K,
    const float* __restrict__ resid) {
  __shared__ unsigned short As[128 * 32];
  __shared__ unsigned short Ws[128 * 32];
  const int tid = threadIdx.x;
  const int bm = blockIdx.y * 128;
  const int bn = blockIdx.x * 128;
  const int lane = tid & 63;
  const int wv = tid >> 6;
  const int wm = (wv >> 1) * 64;
  const int wn = (wv & 1) * 64;
  const int fr = lane & 15;
  const int fs = lane >> 4;  // k-slot 0..3

  // staging assignment: chunk c = 16 bf16 elems; c0 = tid (rows 0..63),
  // c1 = tid+256 (rows 64..127), slot = tid&3, row = tid>>2 (+64)
  const int sA = tid & 3;
  const int r0 = tid >> 2;
  const int r1 = r0 + 64;
  const int ps = sA ^ (r0 & 3);  // physical slot (r1&3 == r0&3)
  const int off0 = r0 * 32 + ps * 8;
  const int off1 = r1 * 32 + ps * 8;

  const float* gA0 = A + (size_t)(bm + r0) * lda + sA * 8;
  const float* gA1 = A + (size_t)(bm + r1) * lda + sA * 8;
  const float* gW0 = W + (size_t)(bn + r0) * ldw + sA * 8;
  const float* gW1 = W + (size_t)(bn + r1) * ldw + sA * 8;

  f32x4 acc[4][4];
#pragma unroll
  for (int i = 0; i < 4; i++)
#pragma unroll
    for (int j = 0; j < 4; j++) acc[i][j] = (f32x4){0.f, 0.f, 0.f, 0.f};

  f32x4 a0a, a0b, a1a, a1b, w0a, w0b, w1a, w1b;
  // prologue: load tile 0
  a0a = *(const f32x4*)(gA0);     a0b = *(const f32x4*)(gA0 + 4);
  a1a = *(const f32x4*)(gA1);     a1b = *(const f32x4*)(gA1 + 4);
  w0a = *(const f32x4*)(gW0);     w0b = *(const f32x4*)(gW0 + 4);
  w1a = *(const f32x4*)(gW1);     w1b = *(const f32x4*)(gW1 + 4);

  const int nk = K >> 5;
  for (int kk = 0; kk < nk; kk++) {
    __syncthreads();  // previous tile fully consumed
    *(short8*)&As[off0] = cvt8(a0a, a0b);
    *(short8*)&As[off1] = cvt8(a1a, a1b);
    *(short8*)&Ws[off0] = cvt8(w0a, w0b);
    *(short8*)&Ws[off1] = cvt8(w1a, w1b);
    __syncthreads();

    if (kk + 1 < nk) {  // issue next-tile loads; overlap with MFMA below
      const int k0 = (kk + 1) * 32;
      a0a = *(const f32x4*)(gA0 + k0); a0b = *(const f32x4*)(gA0 + k0 + 4);
      a1a = *(const f32x4*)(gA1 + k0); a1b = *(const f32x4*)(gA1 + k0 + 4);
      w0a = *(const f32x4*)(gW0 + k0); w0b = *(const f32x4*)(gW0 + k0 + 4);
      w1a = *(const f32x4*)(gW1 + k0); w1b = *(const f32x4*)(gW1 + k0 + 4);
    }

    short8 af[4], bf[4];
#pragma unroll
    for (int i = 0; i < 4; i++) {
      int rowa = wm + i * 16 + fr;
      af[i] = *(const short8*)&As[rowa * 32 + ((fs ^ (rowa & 3)) * 8)];
      int rowb = wn + i * 16 + fr;
      bf[i] = *(const short8*)&Ws[rowb * 32 + ((fs ^ (rowb & 3)) * 8)];
    }
#pragma unroll
    for (int i = 0; i < 4; i++)
#pragma unroll
      for (int j = 0; j < 4; j++)
        acc[i][j] = __builtin_amdgcn_mfma_f32_16x16x32_bf16(af[i], bf[j], acc[i][j], 0, 0, 0);
  }

#pragma unroll
  for (int i = 0; i < 4; i++) {
#pragma unroll
    for (int j = 0; j < 4; j++) {
#pragma unroll
      for (int r = 0; r < 4; r++) {
        int row = bm + wm + i * 16 + fs * 4 + r;
        int col = bn + wn + j * 16 + fr;
        float v = acc[i][j][r];
        if (EPI == 2) v += resid[(size_t)row * ldc + col];
        C[(size_t)row * ldc + col] = v;
      }
    }
  }
}

// ---------------------------------------------------------------------------
// 64x64-tile fallback GEMM (fp32 convert-in-staging) for small/odd N,K.
// EPI 0: plain. EPI 1: softplus(v + bias[col]).
// ---------------------------------------------------------------------------
template<int EPI>
__global__ __launch_bounds__(256) void gemm_bt_k(
    const float* __restrict__ A, int lda,
    const float* __restrict__ W, int ldw,
    float* __restrict__ C, int ldc,
    int M, int N, int K,
    const float* __restrict__ bias) {
  __shared__ unsigned short As[64][40];
  __shared__ unsigned short Ws[64][40];
  const int tid = threadIdx.x;
  const int bm = blockIdx.y * 64;
  const int bn = blockIdx.x * 64;
  const int srow = tid >> 2;
  const int scol = (tid & 3) * 8;
  const int lane = tid & 63;
  const int wv = tid >> 6;
  const int wm = (wv >> 1) * 32;
  const int wn = (wv & 1) * 32;
  const int fr = lane & 15;
  const int fk = (lane >> 4) * 8;

  f32x4 acc[2][2];
#pragma unroll
  for (int i = 0; i < 2; i++)
#pragma unroll
    for (int j = 0; j < 2; j++) acc[i][j] = (f32x4){0.f, 0.f, 0.f, 0.f};

  const int nk = (K + 31) / 32;
  for (int kk = 0; kk < nk; kk++) {
    const int k0 = kk * 32;
    {
      const float* src = A + (size_t)(bm + srow) * lda + k0 + scol;
      unsigned short tmp[8];
      if (k0 + scol + 8 <= K) {
#pragma unroll
        for (int j = 0; j < 8; j++) tmp[j] = f2bf(src[j]);
      } else {
#pragma unroll
        for (int j = 0; j < 8; j++) tmp[j] = (k0 + scol + j < K) ? f2bf(src[j]) : (unsigned short)0;
      }
#pragma unroll
      for (int j = 0; j < 8; j++) As[srow][scol + j] = tmp[j];
    }
    {
      const bool ok = (bn + srow) < N;
      const float* src = W + (size_t)(bn + srow) * ldw + k0 + scol;
      unsigned short tmp[8];
      if (ok && (k0 + scol + 8 <= K)) {
#pragma unroll
        for (int j = 0; j < 8; j++) tmp[j] = f2bf(src[j]);
      } else {
#pragma unroll
        for (int j = 0; j < 8; j++) tmp[j] = (ok && (k0 + scol + j < K)) ? f2bf(src[j]) : (unsigned short)0;
      }
#pragma unroll
      for (int j = 0; j < 8; j++) Ws[srow][scol + j] = tmp[j];
    }
    __syncthreads();

    short8 a0 = *(const short8*)&As[wm + fr][fk];
    short8 a1 = *(const short8*)&As[wm + 16 + fr][fk];
    short8 b0 = *(const short8*)&Ws[wn + fr][fk];
    short8 b1 = *(const short8*)&Ws[wn + 16 + fr][fk];
    acc[0][0] = __builtin_amdgcn_mfma_f32_16x16x32_bf16(a0, b0, acc[0][0], 0, 0, 0);
    acc[0][1] = __builtin_amdgcn_mfma_f32_16x16x32_bf16(a0, b1, acc[0][1], 0, 0, 0);
    acc[1][0] = __builtin_amdgcn_mfma_f32_16x16x32_bf16(a1, b0, acc[1][0], 0, 0, 0);
    acc[1][1] = __builtin_amdgcn_mfma_f32_16x16x32_bf16(a1, b1, acc[1][1], 0, 0, 0);
    __syncthreads();
  }

#pragma unroll
  for (int i = 0; i < 2; i++) {
#pragma unroll
    for (int j = 0; j < 2; j++) {
#pragma unroll
      for (int r = 0; r < 4; r++) {
        int row = bm + wm + i * 16 + (lane >> 4) * 4 + r;
        int col = bn + wn + j * 16 + fr;
        if (col < N) {
          float v = acc[i][j][r];
          if (EPI == 1) {
            float xv = v + bias[col];
            v = (xv > 20.f) ? xv : log1pf(__expf(xv));
          }
          C[(size_t)row * ldc + col] = v;
        }
      }
    }
  }
}

// depthwise causal conv(4) + bias + silu
__global__ __launch_bounds__(256) void conv_silu_k(const float* __restrict__ xz,
                                                   const float* __restrict__ cw,
                                                   const float* __restrict__ cb,
                                                   float* __restrict__ xc) {
  int idx = blockIdx.x * 256 + threadIdx.x;  // NTOK*DI
  int d = idx % DI;
  int m = idx / DI;
  int l = m % SEQ;
  float s = cb[d];
#pragma unroll
  for (int j = 0; j < 4; j++) {
    int tl = l - 3 + j;
    if (tl >= 0) s += xz[(size_t)(m - 3 + j) * (2 * DI) + d] * cw[d * 4 + j];
  }
  float sig = 1.f / (1.f + __expf(-s));
  xc[idx] = s * sig;
}

// chunked scan pass 1
__global__ __launch_bounds__(256) void scan1_k(const float* __restrict__ dt,
                                               const float* __restrict__ xc,
                                               const float* __restrict__ dbc,
                                               const float* __restrict__ A_log_l,
                                               float* __restrict__ cumA,
                                               float* __restrict__ hloc) {
  const int tid = threadIdx.x;
  const int j = blockIdx.x;
  const int cg = blockIdx.y;
  const int b = cg / 6;
  const int d = (cg % 6) * 256 + tid;
  const int c = b * DI + d;

  float Av[DS];
  const float* al = A_log_l + (size_t)d * DS;
#pragma unroll
  for (int s = 0; s < DS; s++) Av[s] = -__expf(al[s]);

  float ap[DS], h[DS];
#pragma unroll
  for (int s = 0; s < DS; s++) { ap[s] = 1.f; h[s] = 0.f; }

  const int t0 = j * CHLEN;
  for (int t = 0; t < CHLEN; t++) {
    int m = b * SEQ + t0 + t;
    float dtv = dt[(size_t)m * DI + d];
    float xv = xc[(size_t)m * DI + d];
    float dtx = dtv * xv;
    const float* bp = dbc + (size_t)m * DBC + NRANK;
#pragma unroll
    for (int s = 0; s < DS; s++) {
      float dA = __expf(dtv * Av[s]);
      h[s] = fmaf(dA, h[s], dtx * bp[s]);
      ap[s] *= dA;
    }
  }
  size_t base = ((size_t)j * (BATCH * DI) + c) * DS;
#pragma unroll
  for (int q = 0; q < 4; q++) {
    *(f32x4*)&cumA[base + q * 4] = (f32x4){ap[q*4], ap[q*4+1], ap[q*4+2], ap[q*4+3]};
    *(f32x4*)&hloc[base + q * 4] = (f32x4){h[q*4], h[q*4+1], h[q*4+2], h[q*4+3]};
  }
}

// pass 2: sequential chunk combine
__global__ __launch_bounds__(256) void scan2_k(const float* __restrict__ cumA,
                                               const float* __restrict__ hloc,
                                               float* __restrict__ hin,
                                               float* __restrict__ states_out) {
  int idx = blockIdx.x * 256 + threadIdx.x;
  const int stride = BATCH * DI * DS;
  float h = 0.f;
  for (int j = 0; j < NCHUNK; j++) {
    hin[(size_t)j * stride + idx] = h;
    h = fmaf(cumA[(size_t)j * stride + idx], h, hloc[(size_t)j * stride + idx]);
  }
  states_out[idx] = h;
}

// pass 3: rerun with true h_in, y = (y + D*xc)*silu(z)
__global__ __launch_bounds__(256) void scan3_k(const float* __restrict__ dt,
                                               const float* __restrict__ xc,
                                               const float* __restrict__ dbc,
                                               const float* __restrict__ xz,
                                               const float* __restrict__ A_log_l,
                                               const float* __restrict__ Dsk,
                                               const float* __restrict__ hin,
                                               float* __restrict__ y) {
  const int tid = threadIdx.x;
  const int j = blockIdx.x;
  const int cg = blockIdx.y;
  const int b = cg / 6;
  const int d = (cg % 6) * 256 + tid;
  const int c = b * DI + d;

  float Av[DS];
  const float* al = A_log_l + (size_t)d * DS;
#pragma unroll
  for (int s = 0; s < DS; s++) Av[s] = -__expf(al[s]);

  float h[DS];
  size_t base = ((size_t)j * (BATCH * DI) + c) * DS;
#pragma unroll
  for (int s = 0; s < DS; s++) h[s] = hin[base + s];

  float dval = Dsk[d];
  const int t0 = j * CHLEN;
  for (int t = 0; t < CHLEN; t++) {
    int m = b * SEQ + t0 + t;
    float dtv = dt[(size_t)m * DI + d];
    float xv = xc[(size_t)m * DI + d];
    float dtx = dtv * xv;
    const float* bp = dbc + (size_t)m * DBC + NRANK;
    const float* cp = bp + DS;
    float ysum = 0.f;
#pragma unroll
    for (int s = 0; s < DS; s++) {
      float dA = __expf(dtv * Av[s]);
      h[s] = fmaf(dA, h[s], dtx * bp[s]);
      ysum = fmaf(h[s], cp[s], ysum);
    }
    float zv = xz[(size_t)m * (2 * DI) + DI + d];
    float sig = 1.f / (1.f + __expf(-zv));
    y[(size_t)m * DI + d] = (ysum + dval * xv) * (zv * sig);
  }
}

// LN (w,b) then optionally LN_noaffine + adaln modulate
template<bool ADA>
__global__ __launch_bounds__(256) void ln_k(const float* __restrict__ in,
                                            const float* __restrict__ w,
                                            const float* __restrict__ bb,
                                            const float* __restrict__ ss,
                                            float* __restrict__ out) {
  __shared__ float red[8];
  const int row = blockIdx.x;
  const int bt = row / SEQ;
  const int tid = threadIdx.x;
  const float* x = in + (size_t)row * DM;
  float v[3];
#pragma unroll
  for (int i = 0; i < 3; i++) v[i] = x[tid + i * 256];
  float s1 = v[0] + v[1] + v[2];
  float s2 = v[0]*v[0] + v[1]*v[1] + v[2]*v[2];
#pragma unroll
  for (int o = 32; o > 0; o >>= 1) { s1 += __shfl_down(s1, o); s2 += __shfl_down(s2, o); }
  int wv = tid >> 6, ln = tid & 63;
  if (ln == 0) { red[wv*2] = s1; red[wv*2+1] = s2; }
  __syncthreads();
  s1 = red[0] + red[2] + red[4] + red[6];
  s2 = red[1] + red[3] + red[5] + red[7];
  float mu = s1 * (1.f / DM);
  float var = s2 * (1.f / DM) - mu * mu;
  float rs = rsqrtf(var + 1e-5f);
  float t[3];
#pragma unroll
  for (int i = 0; i < 3; i++) {
    int c = tid + i * 256;
    t[i] = (v[i] - mu) * rs * w[c] + bb[c];
  }
  if (!ADA) {
#pragma unroll
    for (int i = 0; i < 3; i++) out[(size_t)row * DM + tid + i * 256] = t[i];
    return;
  }
  __syncthreads();
  s1 = t[0] + t[1] + t[2];
  s2 = t[0]*t[0] + t[1]*t[1] + t[2]*t[2];
#pragma unroll
  for (int o = 32; o > 0; o >>= 1) { s1 += __shfl_down(s1, o); s2 += __shfl_down(s2, o); }
  if (ln == 0) { red[wv*2] = s1; red[wv*2+1] = s2; }
  __syncthreads();
  s1 = red[0] + red[2] + red[4] + red[6];
  s2 = red[1] + red[3] + red[5] + red[7];
  float mu2 = s1 * (1.f / DM);
  float var2 = s2 * (1.f / DM) - mu2 * mu2;
  float rs2 = rsqrtf(var2 + 1e-5f);
#pragma unroll
  for (int i = 0; i < 3; i++) {
    int c = tid + i * 256;
    float sc = ss[bt * (2 * DM) + c];
    float sh = ss[bt * (2 * DM) + DM + c];
    out[(size_t)row * DM + c] = (t[i] - mu2) * rs2 * (1.f + sc) + sh;
  }
}

// adaln precompute
__global__ __launch_bounds__(256) void adaln_pre_k(const float* __restrict__ cond,
                                                   const float* __restrict__ aw,
                                                   const float* __restrict__ ab,
                                                   float* __restrict__ ss) {
  int idx = blockIdx.x * 256 + threadIdx.x;
  int e = idx % (2 * DM);
  int b = (idx / (2 * DM)) % BATCH;
  int l = idx / (BATCH * 2 * DM);
  const float* c = cond + b * 128;
  const float* wp = aw + ((size_t)l * (2 * DM) + e) * 128;
  float s = ab[l * (2 * DM) + e];
  for (int k = 0; k < 128; k++) s = fmaf(c[k], wp[k], s);
  ss[idx] = s;
}

extern "C" void kernel_launch(void* const* d_in, const int* in_sizes, int n_in,
                              void* d_out, int out_size, void* d_ws, size_t ws_size,
                              hipStream_t stream) {
  const float* x      = (const float*)d_in[0];
  const float* cond   = (const float*)d_in[1];
  const float* in_w   = (const float*)d_in[2];
  const float* conv_w = (const float*)d_in[3];
  const float* conv_b = (const float*)d_in[4];
  const float* xp_w   = (const float*)d_in[5];
  const float* dtp_w  = (const float*)d_in[6];
  const float* dtp_b  = (const float*)d_in[7];
  const float* A_log  = (const float*)d_in[8];
  const float* Dsk    = (const float*)d_in[9];
  const float* out_w  = (const float*)d_in[10];
  const float* norm_w = (const float*)d_in[11];
  const float* norm_b = (const float*)d_in[12];
  const float* ada_w  = (const float*)d_in[13];
  const float* ada_b  = (const float*)d_in[14];
  const float* fn_w   = (const float*)d_in[15];
  const float* fn_b   = (const float*)d_in[16];

  float* out_h = (float*)d_out;
  float* out_states = out_h + (size_t)NTOK * DM;

  float* p = (float*)d_ws;
  float* h_cur = p; p += (size_t)NTOK * DM;
  float* xz    = p; p += (size_t)NTOK * 2 * DI;
  float* xc    = p; p += (size_t)NTOK * DI;
  float* dbc   = p; p += (size_t)NTOK * DBC;
  float* dtb   = p; p += (size_t)NTOK * DI;
  float* yb    = p; p += (size_t)NTOK * DI;
  float* res2  = p; p += (size_t)NTOK * DM;
  float* cumA  = p; p += (size_t)NCHUNK * BATCH * DI * DS;
  float* hloc  = p; p += (size_t)NCHUNK * BATCH * DI * DS;
  float* hin   = p; p += (size_t)NCHUNK * BATCH * DI * DS;
  float* ss    = p; p += (size_t)NL * BATCH * 2 * DM;

  hipMemcpyAsync(h_cur, x, (size_t)NTOK * DM * sizeof(float),
                 hipMemcpyDeviceToDevice, stream);
  adaln_pre_k<<<72, 256, 0, stream>>>(cond, ada_w, ada_b, ss);

  for (int l = 0; l < NL; l++) {
    // in_proj: (2048x768) x (3072x768)^T -> xz   [128-tile MFMA]
    bt128_k<0><<<dim3(24, 16), 256, 0, stream>>>(
        h_cur, DM, in_w + (size_t)l * 2 * DI * DM, DM, xz, 2 * DI,
        DM, nullptr);
    // conv + silu
    conv_silu_k<<<(NTOK * DI) / 256, 256, 0, stream>>>(
        xz, conv_w + (size_t)l * DI * 4, conv_b + (size_t)l * DI, xc);
    // x_proj: (2048x1536) x (80x1536)^T -> dbc
    gemm_bt_k<0><<<dim3(2, 32), 256, 0, stream>>>(
        xc, DI, xp_w + (size_t)l * DBC * DI, DI, dbc, DBC,
        NTOK, DBC, DI, nullptr);
    // dt_proj + softplus: (2048x48) x (1536x48)^T -> dt
    gemm_bt_k<1><<<dim3(24, 32), 256, 0, stream>>>(
        dbc, DBC, dtp_w + (size_t)l * DI * NRANK, NRANK, dtb, DI,
        NTOK, DI, NRANK, dtp_b + (size_t)l * DI);
    // chunked scan
    scan1_k<<<dim3(NCHUNK, 12), 256, 0, stream>>>(
        dtb, xc, dbc, A_log + (size_t)l * DI * DS, cumA, hloc);
    scan2_k<<<192, 256, 0, stream>>>(
        cumA, hloc, hin, out_states + (size_t)l * BATCH * DI * DS);
    scan3_k<<<dim3(NCHUNK, 12), 256, 0, stream>>>(
        dtb, xc, dbc, xz, A_log + (size_t)l * DI * DS, Dsk + (size_t)l * DI,
        hin, yb);
    // out_proj + residual: (2048x1536) x (768x1536)^T -> res2  [128-tile MFMA]
    bt128_k<2><<<dim3(6, 16), 256, 0, stream>>>(
        yb, DI, out_w + (size_t)l * DM * DI, DI, res2, DM,
        DI, h_cur);
    // LN + adaln modulate -> h_cur
    ln_k<true><<<NTOK, 256, 0, stream>>>(
        res2, norm_w + (size_t)l * DM, norm_b + (size_t)l * DM,
        ss + (size_t)l * BATCH * 2 * DM, h_cur);
  }
  ln_k<false><<<NTOK, 256, 0, stream>>>(h_cur, fn_w, fn_b, nullptr, out_h);
}

// Round 3
// 1121.175 us; speedup vs baseline: 1.3120x; 1.2070x over previous
//
#include <hip/hip_runtime.h>
#include <hip/hip_bf16.h>

#define NL 6
#define DM 768
#define DI 1536
#define DS 16
#define NRANK 48
#define DBC 80
#define BATCH 2
#define SEQ 1024
#define NTOK (BATCH*SEQ)
#define NCHUNK 16
#define CHLEN 64
#define XKS 8          // split-K factor for x_proj
#define XKC (DI/XKS)   // 192 = K-chunk

typedef __attribute__((ext_vector_type(8))) short short8;
typedef __attribute__((ext_vector_type(4))) float f32x4;

__device__ inline unsigned short f2bf(float f) {
  union { float f; unsigned u; } x; x.f = f;
  unsigned r = x.u + 0x7FFF + ((x.u >> 16) & 1);
  return (unsigned short)(r >> 16);
}

__device__ inline short8 cvt8(f32x4 a, f32x4 b) {
  union { short8 s; __hip_bfloat162 h[4]; } u;
  float2 p;
  p.x = a[0]; p.y = a[1]; u.h[0] = __float22bfloat162_rn(p);
  p.x = a[2]; p.y = a[3]; u.h[1] = __float22bfloat162_rn(p);
  p.x = b[0]; p.y = b[1]; u.h[2] = __float22bfloat162_rn(p);
  p.x = b[2]; p.y = b[3]; u.h[3] = __float22bfloat162_rn(p);
  return u.s;
}

// ---------------------------------------------------------------------------
// 128x128-tile bf16 MFMA GEMM, fp32 in (converted in staging), fp32 out.
// C[M,N] = A[M,K] * W[N,K]^T. Requires M%128==0, N%128==0, K%32==0.
// EPI 0: plain store. EPI 2: v + resid[row*ldc+col].
// ---------------------------------------------------------------------------
template<int EPI>
__global__ __launch_bounds__(256) void bt128_k(
    const float* __restrict__ A, int lda,
    const float* __restrict__ W, int ldw,
    float* __restrict__ C, int ldc,
    int K,
    const float* __restrict__ resid) {
  __shared__ unsigned short As[128 * 32];
  __shared__ unsigned short Ws[128 * 32];
  const int tid = threadIdx.x;
  const int bm = blockIdx.y * 128;
  const int bn = blockIdx.x * 128;
  const int lane = tid & 63;
  const int wv = tid >> 6;
  const int wm = (wv >> 1) * 64;
  const int wn = (wv & 1) * 64;
  const int fr = lane & 15;
  const int fs = lane >> 4;

  const int sA = tid & 3;
  const int r0 = tid >> 2;
  const int r1 = r0 + 64;
  const int ps = sA ^ (r0 & 3);
  const int off0 = r0 * 32 + ps * 8;
  const int off1 = r1 * 32 + ps * 8;

  const float* gA0 = A + (size_t)(bm + r0) * lda + sA * 8;
  const float* gA1 = A + (size_t)(bm + r1) * lda + sA * 8;
  const float* gW0 = W + (size_t)(bn + r0) * ldw + sA * 8;
  const float* gW1 = W + (size_t)(bn + r1) * ldw + sA * 8;

  f32x4 acc[4][4];
#pragma unroll
  for (int i = 0; i < 4; i++)
#pragma unroll
    for (int j = 0; j < 4; j++) acc[i][j] = (f32x4){0.f, 0.f, 0.f, 0.f};

  f32x4 a0a, a0b, a1a, a1b, w0a, w0b, w1a, w1b;
  a0a = *(const f32x4*)(gA0);     a0b = *(const f32x4*)(gA0 + 4);
  a1a = *(const f32x4*)(gA1);     a1b = *(const f32x4*)(gA1 + 4);
  w0a = *(const f32x4*)(gW0);     w0b = *(const f32x4*)(gW0 + 4);
  w1a = *(const f32x4*)(gW1);     w1b = *(const f32x4*)(gW1 + 4);

  const int nk = K >> 5;
  for (int kk = 0; kk < nk; kk++) {
    __syncthreads();
    *(short8*)&As[off0] = cvt8(a0a, a0b);
    *(short8*)&As[off1] = cvt8(a1a, a1b);
    *(short8*)&Ws[off0] = cvt8(w0a, w0b);
    *(short8*)&Ws[off1] = cvt8(w1a, w1b);
    __syncthreads();

    if (kk + 1 < nk) {
      const int k0 = (kk + 1) * 32;
      a0a = *(const f32x4*)(gA0 + k0); a0b = *(const f32x4*)(gA0 + k0 + 4);
      a1a = *(const f32x4*)(gA1 + k0); a1b = *(const f32x4*)(gA1 + k0 + 4);
      w0a = *(const f32x4*)(gW0 + k0); w0b = *(const f32x4*)(gW0 + k0 + 4);
      w1a = *(const f32x4*)(gW1 + k0); w1b = *(const f32x4*)(gW1 + k0 + 4);
    }

    short8 af[4], bf[4];
#pragma unroll
    for (int i = 0; i < 4; i++) {
      int rowa = wm + i * 16 + fr;
      af[i] = *(const short8*)&As[rowa * 32 + ((fs ^ (rowa & 3)) * 8)];
      int rowb = wn + i * 16 + fr;
      bf[i] = *(const short8*)&Ws[rowb * 32 + ((fs ^ (rowb & 3)) * 8)];
    }
#pragma unroll
    for (int i = 0; i < 4; i++)
#pragma unroll
      for (int j = 0; j < 4; j++)
        acc[i][j] = __builtin_amdgcn_mfma_f32_16x16x32_bf16(af[i], bf[j], acc[i][j], 0, 0, 0);
  }

#pragma unroll
  for (int i = 0; i < 4; i++) {
#pragma unroll
    for (int j = 0; j < 4; j++) {
#pragma unroll
      for (int r = 0; r < 4; r++) {
        int row = bm + wm + i * 16 + fs * 4 + r;
        int col = bn + wn + j * 16 + fr;
        float v = acc[i][j][r];
        if (EPI == 2) v += resid[(size_t)row * ldc + col];
        C[(size_t)row * ldc + col] = v;
      }
    }
  }
}

// ---------------------------------------------------------------------------
// x_proj split-K: C[2048,80] = A[2048,1536] * W[80,1536]^T.
// grid (XKS, M/64); each block does 64x80 over K-chunk XKC, writes partial.
// ---------------------------------------------------------------------------
__global__ __launch_bounds__(256) void xp_k(
    const float* __restrict__ A,
    const float* __restrict__ W,
    float* __restrict__ part) {
  __shared__ unsigned short As[64][40];
  __shared__ unsigned short Ws[80][40];
  const int tid = threadIdx.x;
  const int ks = blockIdx.x;
  const int bm = blockIdx.y * 64;
  const int lane = tid & 63;
  const int wv = tid >> 6;
  const int fr = lane & 15;
  const int fs = lane >> 4;
  const int fk = fs * 8;

  const int ar = tid >> 2;
  const int ac = (tid & 3) * 8;
  const int k0base = ks * XKC;

  const float* gA  = A + (size_t)(bm + ar) * DI + k0base + ac;
  const float* gW0 = W + (size_t)ar * DI + k0base + ac;
  const float* gW1 = W + (size_t)(64 + ar) * DI + k0base + ac;  // tid<64 only

  f32x4 acc[5];
#pragma unroll
  for (int n = 0; n < 5; n++) acc[n] = (f32x4){0.f, 0.f, 0.f, 0.f};

  f32x4 aA, aB, w0A, w0B, w1A, w1B;
  aA = *(const f32x4*)(gA);   aB = *(const f32x4*)(gA + 4);
  w0A = *(const f32x4*)(gW0); w0B = *(const f32x4*)(gW0 + 4);
  if (tid < 64) { w1A = *(const f32x4*)(gW1); w1B = *(const f32x4*)(gW1 + 4); }

  const int nk = XKC / 32;  // 6
  for (int kk = 0; kk < nk; kk++) {
    __syncthreads();
    *(short8*)&As[ar][ac] = cvt8(aA, aB);
    *(short8*)&Ws[ar][ac] = cvt8(w0A, w0B);
    if (tid < 64) *(short8*)&Ws[64 + ar][ac] = cvt8(w1A, w1B);
    __syncthreads();

    if (kk + 1 < nk) {
      const int k0 = (kk + 1) * 32;
      aA = *(const f32x4*)(gA + k0);   aB = *(const f32x4*)(gA + k0 + 4);
      w0A = *(const f32x4*)(gW0 + k0); w0B = *(const f32x4*)(gW0 + k0 + 4);
      if (tid < 64) { w1A = *(const f32x4*)(gW1 + k0); w1B = *(const f32x4*)(gW1 + k0 + 4); }
    }

    short8 af = *(const short8*)&As[wv * 16 + fr][fk];
#pragma unroll
    for (int n = 0; n < 5; n++) {
      short8 bf = *(const short8*)&Ws[n * 16 + fr][fk];
      acc[n] = __builtin_amdgcn_mfma_f32_16x16x32_bf16(af, bf, acc[n], 0, 0, 0);
    }
  }

#pragma unroll
  for (int n = 0; n < 5; n++) {
#pragma unroll
    for (int r = 0; r < 4; r++) {
      int row = bm + wv * 16 + fs * 4 + r;
      part[((size_t)ks * NTOK + row) * DBC + n * 16 + fr] = acc[n][r];
    }
  }
}

// sum XKS partials -> dbc
__global__ __launch_bounds__(256) void xp_reduce_k(const float* __restrict__ part,
                                                   float* __restrict__ dbc) {
  int i = blockIdx.x * 256 + threadIdx.x;  // NTOK*DBC/4 = 40960
  const f32x4* p4 = (const f32x4*)part;
  const int stride4 = NTOK * DBC / 4;
  f32x4 s = p4[i];
#pragma unroll
  for (int ks = 1; ks < XKS; ks++) {
    f32x4 v = p4[(size_t)ks * stride4 + i];
    s[0] += v[0]; s[1] += v[1]; s[2] += v[2]; s[3] += v[3];
  }
  ((f32x4*)dbc)[i] = s;
}

// ---------------------------------------------------------------------------
// 64x64-tile fallback GEMM. EPI 0: plain. EPI 1: softplus(v + bias[col]).
// ---------------------------------------------------------------------------
template<int EPI>
__global__ __launch_bounds__(256) void gemm_bt_k(
    const float* __restrict__ A, int lda,
    const float* __restrict__ W, int ldw,
    float* __restrict__ C, int ldc,
    int M, int N, int K,
    const float* __restrict__ bias) {
  __shared__ unsigned short As[64][40];
  __shared__ unsigned short Ws[64][40];
  const int tid = threadIdx.x;
  const int bm = blockIdx.y * 64;
  const int bn = blockIdx.x * 64;
  const int srow = tid >> 2;
  const int scol = (tid & 3) * 8;
  const int lane = tid & 63;
  const int wv = tid >> 6;
  const int wm = (wv >> 1) * 32;
  const int wn = (wv & 1) * 32;
  const int fr = lane & 15;
  const int fk = (lane >> 4) * 8;

  f32x4 acc[2][2];
#pragma unroll
  for (int i = 0; i < 2; i++)
#pragma unroll
    for (int j = 0; j < 2; j++) acc[i][j] = (f32x4){0.f, 0.f, 0.f, 0.f};

  const int nk = (K + 31) / 32;
  for (int kk = 0; kk < nk; kk++) {
    const int k0 = kk * 32;
    {
      const float* src = A + (size_t)(bm + srow) * lda + k0 + scol;
      unsigned short tmp[8];
      if (k0 + scol + 8 <= K) {
#pragma unroll
        for (int j = 0; j < 8; j++) tmp[j] = f2bf(src[j]);
      } else {
#pragma unroll
        for (int j = 0; j < 8; j++) tmp[j] = (k0 + scol + j < K) ? f2bf(src[j]) : (unsigned short)0;
      }
#pragma unroll
      for (int j = 0; j < 8; j++) As[srow][scol + j] = tmp[j];
    }
    {
      const bool ok = (bn + srow) < N;
      const float* src = W + (size_t)(bn + srow) * ldw + k0 + scol;
      unsigned short tmp[8];
      if (ok && (k0 + scol + 8 <= K)) {
#pragma unroll
        for (int j = 0; j < 8; j++) tmp[j] = f2bf(src[j]);
      } else {
#pragma unroll
        for (int j = 0; j < 8; j++) tmp[j] = (ok && (k0 + scol + j < K)) ? f2bf(src[j]) : (unsigned short)0;
      }
#pragma unroll
      for (int j = 0; j < 8; j++) Ws[srow][scol + j] = tmp[j];
    }
    __syncthreads();

    short8 a0 = *(const short8*)&As[wm + fr][fk];
    short8 a1 = *(const short8*)&As[wm + 16 + fr][fk];
    short8 b0 = *(const short8*)&Ws[wn + fr][fk];
    short8 b1 = *(const short8*)&Ws[wn + 16 + fr][fk];
    acc[0][0] = __builtin_amdgcn_mfma_f32_16x16x32_bf16(a0, b0, acc[0][0], 0, 0, 0);
    acc[0][1] = __builtin_amdgcn_mfma_f32_16x16x32_bf16(a0, b1, acc[0][1], 0, 0, 0);
    acc[1][0] = __builtin_amdgcn_mfma_f32_16x16x32_bf16(a1, b0, acc[1][0], 0, 0, 0);
    acc[1][1] = __builtin_amdgcn_mfma_f32_16x16x32_bf16(a1, b1, acc[1][1], 0, 0, 0);
    __syncthreads();
  }

#pragma unroll
  for (int i = 0; i < 2; i++) {
#pragma unroll
    for (int j = 0; j < 2; j++) {
#pragma unroll
      for (int r = 0; r < 4; r++) {
        int row = bm + wm + i * 16 + (lane >> 4) * 4 + r;
        int col = bn + wn + j * 16 + fr;
        if (col < N) {
          float v = acc[i][j][r];
          if (EPI == 1) {
            float xv = v + bias[col];
            v = (xv > 20.f) ? xv : log1pf(__expf(xv));
          }
          C[(size_t)row * ldc + col] = v;
        }
      }
    }
  }
}

// depthwise causal conv(4) + bias + silu
__global__ __launch_bounds__(256) void conv_silu_k(const float* __restrict__ xz,
                                                   const float* __restrict__ cw,
                                                   const float* __restrict__ cb,
                                                   float* __restrict__ xc) {
  int idx = blockIdx.x * 256 + threadIdx.x;
  int d = idx % DI;
  int m = idx / DI;
  int l = m % SEQ;
  float s = cb[d];
#pragma unroll
  for (int j = 0; j < 4; j++) {
    int tl = l - 3 + j;
    if (tl >= 0) s += xz[(size_t)(m - 3 + j) * (2 * DI) + d] * cw[d * 4 + j];
  }
  float sig = 1.f / (1.f + __expf(-s));
  xc[idx] = s * sig;
}

// chunked scan pass 1
__global__ __launch_bounds__(256) void scan1_k(const float* __restrict__ dt,
                                               const float* __restrict__ xc,
                                               const float* __restrict__ dbc,
                                               const float* __restrict__ A_log_l,
                                               float* __restrict__ cumA,
                                               float* __restrict__ hloc) {
  const int tid = threadIdx.x;
  const int j = blockIdx.x;
  const int cg = blockIdx.y;
  const int b = cg / 6;
  const int d = (cg % 6) * 256 + tid;
  const int c = b * DI + d;

  float Av[DS];
  const float* al = A_log_l + (size_t)d * DS;
#pragma unroll
  for (int s = 0; s < DS; s++) Av[s] = -__expf(al[s]);

  float ap[DS], h[DS];
#pragma unroll
  for (int s = 0; s < DS; s++) { ap[s] = 1.f; h[s] = 0.f; }

  const int t0 = j * CHLEN;
  for (int t = 0; t < CHLEN; t++) {
    int m = b * SEQ + t0 + t;
    float dtv = dt[(size_t)m * DI + d];
    float xv = xc[(size_t)m * DI + d];
    float dtx = dtv * xv;
    const float* bp = dbc + (size_t)m * DBC + NRANK;
#pragma unroll
    for (int s = 0; s < DS; s++) {
      float dA = __expf(dtv * Av[s]);
      h[s] = fmaf(dA, h[s], dtx * bp[s]);
      ap[s] *= dA;
    }
  }
  size_t base = ((size_t)j * (BATCH * DI) + c) * DS;
#pragma unroll
  for (int q = 0; q < 4; q++) {
    *(f32x4*)&cumA[base + q * 4] = (f32x4){ap[q*4], ap[q*4+1], ap[q*4+2], ap[q*4+3]};
    *(f32x4*)&hloc[base + q * 4] = (f32x4){h[q*4], h[q*4+1], h[q*4+2], h[q*4+3]};
  }
}

// pass 2: sequential chunk combine
__global__ __launch_bounds__(256) void scan2_k(const float* __restrict__ cumA,
                                               const float* __restrict__ hloc,
                                               float* __restrict__ hin,
                                               float* __restrict__ states_out) {
  int idx = blockIdx.x * 256 + threadIdx.x;
  const int stride = BATCH * DI * DS;
  float h = 0.f;
  for (int j = 0; j < NCHUNK; j++) {
    hin[(size_t)j * stride + idx] = h;
    h = fmaf(cumA[(size_t)j * stride + idx], h, hloc[(size_t)j * stride + idx]);
  }
  states_out[idx] = h;
}

// pass 3: rerun with true h_in, y = (y + D*xc)*silu(z)
__global__ __launch_bounds__(256) void scan3_k(const float* __restrict__ dt,
                                               const float* __restrict__ xc,
                                               const float* __restrict__ dbc,
                                               const float* __restrict__ xz,
                                               const float* __restrict__ A_log_l,
                                               const float* __restrict__ Dsk,
                                               const float* __restrict__ hin,
                                               float* __restrict__ y) {
  const int tid = threadIdx.x;
  const int j = blockIdx.x;
  const int cg = blockIdx.y;
  const int b = cg / 6;
  const int d = (cg % 6) * 256 + tid;
  const int c = b * DI + d;

  float Av[DS];
  const float* al = A_log_l + (size_t)d * DS;
#pragma unroll
  for (int s = 0; s < DS; s++) Av[s] = -__expf(al[s]);

  float h[DS];
  size_t base = ((size_t)j * (BATCH * DI) + c) * DS;
#pragma unroll
  for (int s = 0; s < DS; s++) h[s] = hin[base + s];

  float dval = Dsk[d];
  const int t0 = j * CHLEN;
  for (int t = 0; t < CHLEN; t++) {
    int m = b * SEQ + t0 + t;
    float dtv = dt[(size_t)m * DI + d];
    float xv = xc[(size_t)m * DI + d];
    float dtx = dtv * xv;
    const float* bp = dbc + (size_t)m * DBC + NRANK;
    const float* cp = bp + DS;
    float ysum = 0.f;
#pragma unroll
    for (int s = 0; s < DS; s++) {
      float dA = __expf(dtv * Av[s]);
      h[s] = fmaf(dA, h[s], dtx * bp[s]);
      ysum = fmaf(h[s], cp[s], ysum);
    }
    float zv = xz[(size_t)m * (2 * DI) + DI + d];
    float sig = 1.f / (1.f + __expf(-zv));
    y[(size_t)m * DI + d] = (ysum + dval * xv) * (zv * sig);
  }
}

// LN (w,b) then optionally LN_noaffine + adaln modulate
template<bool ADA>
__global__ __launch_bounds__(256) void ln_k(const float* __restrict__ in,
                                            const float* __restrict__ w,
                                            const float* __restrict__ bb,
                                            const float* __restrict__ ss,
                                            float* __restrict__ out) {
  __shared__ float red[8];
  const int row = blockIdx.x;
  const int bt = row / SEQ;
  const int tid = threadIdx.x;
  const float* x = in + (size_t)row * DM;
  float v[3];
#pragma unroll
  for (int i = 0; i < 3; i++) v[i] = x[tid + i * 256];
  float s1 = v[0] + v[1] + v[2];
  float s2 = v[0]*v[0] + v[1]*v[1] + v[2]*v[2];
#pragma unroll
  for (int o = 32; o > 0; o >>= 1) { s1 += __shfl_down(s1, o); s2 += __shfl_down(s2, o); }
  int wv = tid >> 6, ln = tid & 63;
  if (ln == 0) { red[wv*2] = s1; red[wv*2+1] = s2; }
  __syncthreads();
  s1 = red[0] + red[2] + red[4] + red[6];
  s2 = red[1] + red[3] + red[5] + red[7];
  float mu = s1 * (1.f / DM);
  float var = s2 * (1.f / DM) - mu * mu;
  float rs = rsqrtf(var + 1e-5f);
  float t[3];
#pragma unroll
  for (int i = 0; i < 3; i++) {
    int c = tid + i * 256;
    t[i] = (v[i] - mu) * rs * w[c] + bb[c];
  }
  if (!ADA) {
#pragma unroll
    for (int i = 0; i < 3; i++) out[(size_t)row * DM + tid + i * 256] = t[i];
    return;
  }
  __syncthreads();
  s1 = t[0] + t[1] + t[2];
  s2 = t[0]*t[0] + t[1]*t[1] + t[2]*t[2];
#pragma unroll
  for (int o = 32; o > 0; o >>= 1) { s1 += __shfl_down(s1, o); s2 += __shfl_down(s2, o); }
  if (ln == 0) { red[wv*2] = s1; red[wv*2+1] = s2; }
  __syncthreads();
  s1 = red[0] + red[2] + red[4] + red[6];
  s2 = red[1] + red[3] + red[5] + red[7];
  float mu2 = s1 * (1.f / DM);
  float var2 = s2 * (1.f / DM) - mu2 * mu2;
  float rs2 = rsqrtf(var2 + 1e-5f);
#pragma unroll
  for (int i = 0; i < 3; i++) {
    int c = tid + i * 256;
    float sc = ss[bt * (2 * DM) + c];
    float sh = ss[bt * (2 * DM) + DM + c];
    out[(size_t)row * DM + c] = (t[i] - mu2) * rs2 * (1.f + sc) + sh;
  }
}

// adaln precompute
__global__ __launch_bounds__(256) void adaln_pre_k(const float* __restrict__ cond,
                                                   const float* __restrict__ aw,
                                                   const float* __restrict__ ab,
                                                   float* __restrict__ ss) {
  int idx = blockIdx.x * 256 + threadIdx.x;
  int e = idx % (2 * DM);
  int b = (idx / (2 * DM)) % BATCH;
  int l = idx / (BATCH * 2 * DM);
  const float* c = cond + b * 128;
  const float* wp = aw + ((size_t)l * (2 * DM) + e) * 128;
  float s = ab[l * (2 * DM) + e];
  for (int k = 0; k < 128; k++) s = fmaf(c[k], wp[k], s);
  ss[idx] = s;
}

extern "C" void kernel_launch(void* const* d_in, const int* in_sizes, int n_in,
                              void* d_out, int out_size, void* d_ws, size_t ws_size,
                              hipStream_t stream) {
  const float* x      = (const float*)d_in[0];
  const float* cond   = (const float*)d_in[1];
  const float* in_w   = (const float*)d_in[2];
  const float* conv_w = (const float*)d_in[3];
  const float* conv_b = (const float*)d_in[4];
  const float* xp_w   = (const float*)d_in[5];
  const float* dtp_w  = (const float*)d_in[6];
  const float* dtp_b  = (const float*)d_in[7];
  const float* A_log  = (const float*)d_in[8];
  const float* Dsk    = (const float*)d_in[9];
  const float* out_w  = (const float*)d_in[10];
  const float* norm_w = (const float*)d_in[11];
  const float* norm_b = (const float*)d_in[12];
  const float* ada_w  = (const float*)d_in[13];
  const float* ada_b  = (const float*)d_in[14];
  const float* fn_w   = (const float*)d_in[15];
  const float* fn_b   = (const float*)d_in[16];

  float* out_h = (float*)d_out;
  float* out_states = out_h + (size_t)NTOK * DM;

  float* p = (float*)d_ws;
  float* h_cur = p; p += (size_t)NTOK * DM;
  float* xz    = p; p += (size_t)NTOK * 2 * DI;
  float* xc    = p; p += (size_t)NTOK * DI;
  float* dbc   = p; p += (size_t)NTOK * DBC;
  float* dtb   = p; p += (size_t)NTOK * DI;
  float* yb    = p; p += (size_t)NTOK * DI;
  float* res2  = p; p += (size_t)NTOK * DM;
  float* cumA  = p; p += (size_t)NCHUNK * BATCH * DI * DS;
  float* hloc  = p; p += (size_t)NCHUNK * BATCH * DI * DS;
  float* hin   = p; p += (size_t)NCHUNK * BATCH * DI * DS;
  float* ss    = p; p += (size_t)NL * BATCH * 2 * DM;
  float* xpart = p; p += (size_t)XKS * NTOK * DBC;

  hipMemcpyAsync(h_cur, x, (size_t)NTOK * DM * sizeof(float),
                 hipMemcpyDeviceToDevice, stream);
  adaln_pre_k<<<72, 256, 0, stream>>>(cond, ada_w, ada_b, ss);

  for (int l = 0; l < NL; l++) {
    // in_proj: (2048x768) x (3072x768)^T -> xz   [128-tile MFMA]
    bt128_k<0><<<dim3(24, 16), 256, 0, stream>>>(
        h_cur, DM, in_w + (size_t)l * 2 * DI * DM, DM, xz, 2 * DI,
        DM, nullptr);
    // conv + silu
    conv_silu_k<<<(NTOK * DI) / 256, 256, 0, stream>>>(
        xz, conv_w + (size_t)l * DI * 4, conv_b + (size_t)l * DI, xc);
    // x_proj split-K: (2048x1536) x (80x1536)^T -> dbc
    xp_k<<<dim3(XKS, NTOK / 64), 256, 0, stream>>>(
        xc, xp_w + (size_t)l * DBC * DI, xpart);
    xp_reduce_k<<<NTOK * DBC / 4 / 256, 256, 0, stream>>>(xpart, dbc);
    // dt_proj + softplus: (2048x48) x (1536x48)^T -> dt
    gemm_bt_k<1><<<dim3(24, 32), 256, 0, stream>>>(
        dbc, DBC, dtp_w + (size_t)l * DI * NRANK, NRANK, dtb, DI,
        NTOK, DI, NRANK, dtp_b + (size_t)l * DI);
    // chunked scan
    scan1_k<<<dim3(NCHUNK, 12), 256, 0, stream>>>(
        dtb, xc, dbc, A_log + (size_t)l * DI * DS, cumA, hloc);
    scan2_k<<<192, 256, 0, stream>>>(
        cumA, hloc, hin, out_states + (size_t)l * BATCH * DI * DS);
    scan3_k<<<dim3(NCHUNK, 12), 256, 0, stream>>>(
        dtb, xc, dbc, xz, A_log + (size_t)l * DI * DS, Dsk + (size_t)l * DI,
        hin, yb);
    // out_proj + residual: (2048x1536) x (768x1536)^T -> res2  [128-tile MFMA]
    bt128_k<2><<<dim3(6, 16), 256, 0, stream>>>(
        yb, DI, out_w + (size_t)l * DM * DI, DI, res2, DM,
        DI, h_cur);
    // LN + adaln modulate -> h_cur
    ln_k<true><<<NTOK, 256, 0, stream>>>(
        res2, norm_w + (size_t)l * DM, norm_b + (size_t)l * DM,
        ss + (size_t)l * BATCH * 2 * DM, h_cur);
  }
  ln_k<false><<<NTOK, 256, 0, stream>>>(h_cur, fn_w, fn_b, nullptr, out_h);
}

// Round 4
// 1100.598 us; speedup vs baseline: 1.3365x; 1.0187x over previous
//
#include <hip/hip_runtime.h>
#include <hip/hip_bf16.h>

#define NL 6
#define DM 768
#define DI 1536
#define DS 16
#define NRANK 48
#define DBC 80
#define BATCH 2
#define SEQ 1024
#define NTOK (BATCH*SEQ)
#define NCHUNK 16
#define CHLEN 64
#define XKS 8
#define XKC (DI/XKS)

typedef __attribute__((ext_vector_type(8))) short short8;
typedef __attribute__((ext_vector_type(4))) float f32x4;
typedef __attribute__((ext_vector_type(4))) unsigned short ushort4v;

__device__ inline unsigned short f2bf(float f) {
  union { float f; unsigned u; } x; x.f = f;
  unsigned r = x.u + 0x7FFF + ((x.u >> 16) & 1);
  return (unsigned short)(r >> 16);
}

__device__ inline void gl_lds16(const unsigned short* g, unsigned short* l) {
  __builtin_amdgcn_global_load_lds(
      (const __attribute__((address_space(1))) unsigned int*)(g),
      (__attribute__((address_space(3))) unsigned int*)(l),
      16, 0, 0);
}

// fp32 -> bf16 bulk convert (16B loads, 8B stores), grid-stride
__global__ __launch_bounds__(256) void f2b_k(const float* __restrict__ src,
                                             unsigned short* __restrict__ dst,
                                             int n4) {
  for (int i = blockIdx.x * 256 + threadIdx.x; i < n4; i += gridDim.x * 256) {
    f32x4 v = ((const f32x4*)src)[i];
    union { ushort4v u4; __hip_bfloat162 h[2]; } u;
    float2 p;
    p.x = v[0]; p.y = v[1]; u.h[0] = __float22bfloat162_rn(p);
    p.x = v[2]; p.y = v[3]; u.h[1] = __float22bfloat162_rn(p);
    ((ushort4v*)dst)[i] = u.u4;
  }
}

// ---------------------------------------------------------------------------
// 128x128-tile bf16 GEMM, bf16 inputs, global_load_lds staging (16B),
// double-buffered LDS, pre-swizzled global source (LDS dest linear).
// C[M,N] = A[M,K] * W[N,K]^T, fp32 out. M%128==0, N%128==0, K%32==0.
// EPI 0: plain. EPI 2: v + resid[row*ldc+col].
// ---------------------------------------------------------------------------
template<int EPI>
__global__ __launch_bounds__(256) void bt128b_k(
    const unsigned short* __restrict__ A, int lda,
    const unsigned short* __restrict__ W, int ldw,
    float* __restrict__ C, int ldc,
    int K,
    const float* __restrict__ resid) {
  __shared__ __align__(16) unsigned short As[2][128 * 32];
  __shared__ __align__(16) unsigned short Ws[2][128 * 32];
  const int tid = threadIdx.x;
  const int bm = blockIdx.y * 128;
  const int bn = blockIdx.x * 128;
  const int lane = tid & 63;
  const int wv = tid >> 6;
  const int wm = (wv >> 1) * 64;
  const int wn = (wv & 1) * 64;
  const int fr = lane & 15;
  const int fs = lane >> 4;

  // staging: chunk c (16B) at LDS offset c*16; c0 = tid (rows 0..63),
  // c1 = tid+256 (rows 64..127). phys slot p = tid&3; logical slot s = p^(r&3)
  // is fetched from global so that read-side swizzle finds slot fs at
  // phys p = fs^(row&3).
  const int r0 = tid >> 2;
  const int s0 = (tid & 3) ^ (r0 & 3);  // rows r0 and r0+64 share (r&3)

  const unsigned short* gA0 = A + (size_t)(bm + r0) * lda + s0 * 8;
  const unsigned short* gA1 = A + (size_t)(bm + r0 + 64) * lda + s0 * 8;
  const unsigned short* gW0 = W + (size_t)(bn + r0) * ldw + s0 * 8;
  const unsigned short* gW1 = W + (size_t)(bn + r0 + 64) * ldw + s0 * 8;

  f32x4 acc[4][4];
#pragma unroll
  for (int i = 0; i < 4; i++)
#pragma unroll
    for (int j = 0; j < 4; j++) acc[i][j] = (f32x4){0.f, 0.f, 0.f, 0.f};

  // prologue: stage tile 0 into buf 0
  gl_lds16(gA0, &As[0][0] + tid * 8);
  gl_lds16(gA1, &As[0][2048] + tid * 8);
  gl_lds16(gW0, &Ws[0][0] + tid * 8);
  gl_lds16(gW1, &Ws[0][2048] + tid * 8);
  __syncthreads();

  const int nk = K >> 5;
  int buf = 0;
  for (int kk = 0; kk < nk; kk++) {
    if (kk + 1 < nk) {
      const int k0 = (kk + 1) * 32;
      gl_lds16(gA0 + k0, &As[buf ^ 1][0] + tid * 8);
      gl_lds16(gA1 + k0, &As[buf ^ 1][2048] + tid * 8);
      gl_lds16(gW0 + k0, &Ws[buf ^ 1][0] + tid * 8);
      gl_lds16(gW1 + k0, &Ws[buf ^ 1][2048] + tid * 8);
    }

    short8 af[4], bf[4];
#pragma unroll
    for (int i = 0; i < 4; i++) {
      int rowa = wm + i * 16 + fr;
      af[i] = *(const short8*)&As[buf][rowa * 32 + ((fs ^ (rowa & 3)) * 8)];
      int rowb = wn + i * 16 + fr;
      bf[i] = *(const short8*)&Ws[buf][rowb * 32 + ((fs ^ (rowb & 3)) * 8)];
    }
#pragma unroll
    for (int i = 0; i < 4; i++)
#pragma unroll
      for (int j = 0; j < 4; j++)
        acc[i][j] = __builtin_amdgcn_mfma_f32_16x16x32_bf16(af[i], bf[j], acc[i][j], 0, 0, 0);

    __syncthreads();  // drains vmcnt(0): next buffer staged, this buffer free
    buf ^= 1;
  }

#pragma unroll
  for (int i = 0; i < 4; i++) {
#pragma unroll
    for (int j = 0; j < 4; j++) {
#pragma unroll
      for (int r = 0; r < 4; r++) {
        int row = bm + wm + i * 16 + fs * 4 + r;
        int col = bn + wn + j * 16 + fr;
        float v = acc[i][j][r];
        if (EPI == 2) v += resid[(size_t)row * ldc + col];
        C[(size_t)row * ldc + col] = v;
      }
    }
  }
}

// ---------------------------------------------------------------------------
// x_proj split-K, bf16 inputs: C[2048,80] = A[2048,1536] * W[80,1536]^T
// ---------------------------------------------------------------------------
__global__ __launch_bounds__(256) void xp_k(
    const unsigned short* __restrict__ A,
    const unsigned short* __restrict__ W,
    float* __restrict__ part) {
  __shared__ __align__(16) unsigned short As[64][40];
  __shared__ __align__(16) unsigned short Ws[80][40];
  const int tid = threadIdx.x;
  const int ks = blockIdx.x;
  const int bm = blockIdx.y * 64;
  const int lane = tid & 63;
  const int wv = tid >> 6;
  const int fr = lane & 15;
  const int fs = lane >> 4;
  const int fk = fs * 8;

  const int ar = tid >> 2;
  const int ac = (tid & 3) * 8;
  const int k0base = ks * XKC;

  const unsigned short* gA  = A + (size_t)(bm + ar) * DI + k0base + ac;
  const unsigned short* gW0 = W + (size_t)ar * DI + k0base + ac;
  const unsigned short* gW1 = W + (size_t)(64 + ar) * DI + k0base + ac;

  f32x4 acc[5];
#pragma unroll
  for (int n = 0; n < 5; n++) acc[n] = (f32x4){0.f, 0.f, 0.f, 0.f};

  short8 aA, w0A, w1A;
  aA = *(const short8*)(gA);
  w0A = *(const short8*)(gW0);
  if (tid < 64) w1A = *(const short8*)(gW1);

  const int nk = XKC / 32;  // 6
  for (int kk = 0; kk < nk; kk++) {
    __syncthreads();
    *(short8*)&As[ar][ac] = aA;
    *(short8*)&Ws[ar][ac] = w0A;
    if (tid < 64) *(short8*)&Ws[64 + ar][ac] = w1A;
    __syncthreads();

    if (kk + 1 < nk) {
      const int k0 = (kk + 1) * 32;
      aA = *(const short8*)(gA + k0);
      w0A = *(const short8*)(gW0 + k0);
      if (tid < 64) w1A = *(const short8*)(gW1 + k0);
    }

    short8 af = *(const short8*)&As[wv * 16 + fr][fk];
#pragma unroll
    for (int n = 0; n < 5; n++) {
      short8 bf = *(const short8*)&Ws[n * 16 + fr][fk];
      acc[n] = __builtin_amdgcn_mfma_f32_16x16x32_bf16(af, bf, acc[n], 0, 0, 0);
    }
  }

#pragma unroll
  for (int n = 0; n < 5; n++) {
#pragma unroll
    for (int r = 0; r < 4; r++) {
      int row = bm + wv * 16 + fs * 4 + r;
      part[((size_t)ks * NTOK + row) * DBC + n * 16 + fr] = acc[n][r];
    }
  }
}

// sum XKS partials -> dbc
__global__ __launch_bounds__(256) void xp_reduce_k(const float* __restrict__ part,
                                                   float* __restrict__ dbc) {
  int i = blockIdx.x * 256 + threadIdx.x;
  const f32x4* p4 = (const f32x4*)part;
  const int stride4 = NTOK * DBC / 4;
  f32x4 s = p4[i];
#pragma unroll
  for (int ks = 1; ks < XKS; ks++) {
    f32x4 v = p4[(size_t)ks * stride4 + i];
    s[0] += v[0]; s[1] += v[1]; s[2] += v[2]; s[3] += v[3];
  }
  ((f32x4*)dbc)[i] = s;
}

// ---------------------------------------------------------------------------
// 64x64-tile fp32-input GEMM (dt_proj only). EPI 1: softplus(v + bias[col]).
// ---------------------------------------------------------------------------
template<int EPI>
__global__ __launch_bounds__(256) void gemm_bt_k(
    const float* __restrict__ A, int lda,
    const float* __restrict__ W, int ldw,
    float* __restrict__ C, int ldc,
    int M, int N, int K,
    const float* __restrict__ bias) {
  __shared__ unsigned short As[64][40];
  __shared__ unsigned short Ws[64][40];
  const int tid = threadIdx.x;
  const int bm = blockIdx.y * 64;
  const int bn = blockIdx.x * 64;
  const int srow = tid >> 2;
  const int scol = (tid & 3) * 8;
  const int lane = tid & 63;
  const int wv = tid >> 6;
  const int wm = (wv >> 1) * 32;
  const int wn = (wv & 1) * 32;
  const int fr = lane & 15;
  const int fk = (lane >> 4) * 8;

  f32x4 acc[2][2];
#pragma unroll
  for (int i = 0; i < 2; i++)
#pragma unroll
    for (int j = 0; j < 2; j++) acc[i][j] = (f32x4){0.f, 0.f, 0.f, 0.f};

  const int nk = (K + 31) / 32;
  for (int kk = 0; kk < nk; kk++) {
    const int k0 = kk * 32;
    {
      const float* src = A + (size_t)(bm + srow) * lda + k0 + scol;
      unsigned short tmp[8];
      if (k0 + scol + 8 <= K) {
#pragma unroll
        for (int j = 0; j < 8; j++) tmp[j] = f2bf(src[j]);
      } else {
#pragma unroll
        for (int j = 0; j < 8; j++) tmp[j] = (k0 + scol + j < K) ? f2bf(src[j]) : (unsigned short)0;
      }
#pragma unroll
      for (int j = 0; j < 8; j++) As[srow][scol + j] = tmp[j];
    }
    {
      const bool ok = (bn + srow) < N;
      const float* src = W + (size_t)(bn + srow) * ldw + k0 + scol;
      unsigned short tmp[8];
      if (ok && (k0 + scol + 8 <= K)) {
#pragma unroll
        for (int j = 0; j < 8; j++) tmp[j] = f2bf(src[j]);
      } else {
#pragma unroll
        for (int j = 0; j < 8; j++) tmp[j] = (ok && (k0 + scol + j < K)) ? f2bf(src[j]) : (unsigned short)0;
      }
#pragma unroll
      for (int j = 0; j < 8; j++) Ws[srow][scol + j] = tmp[j];
    }
    __syncthreads();

    short8 a0 = *(const short8*)&As[wm + fr][fk];
    short8 a1 = *(const short8*)&As[wm + 16 + fr][fk];
    short8 b0 = *(const short8*)&Ws[wn + fr][fk];
    short8 b1 = *(const short8*)&Ws[wn + 16 + fr][fk];
    acc[0][0] = __builtin_amdgcn_mfma_f32_16x16x32_bf16(a0, b0, acc[0][0], 0, 0, 0);
    acc[0][1] = __builtin_amdgcn_mfma_f32_16x16x32_bf16(a0, b1, acc[0][1], 0, 0, 0);
    acc[1][0] = __builtin_amdgcn_mfma_f32_16x16x32_bf16(a1, b0, acc[1][0], 0, 0, 0);
    acc[1][1] = __builtin_amdgcn_mfma_f32_16x16x32_bf16(a1, b1, acc[1][1], 0, 0, 0);
    __syncthreads();
  }

#pragma unroll
  for (int i = 0; i < 2; i++) {
#pragma unroll
    for (int j = 0; j < 2; j++) {
#pragma unroll
      for (int r = 0; r < 4; r++) {
        int row = bm + wm + i * 16 + (lane >> 4) * 4 + r;
        int col = bn + wn + j * 16 + fr;
        if (col < N) {
          float v = acc[i][j][r];
          if (EPI == 1) {
            float xv = v + bias[col];
            v = (xv > 20.f) ? xv : log1pf(__expf(xv));
          }
          C[(size_t)row * ldc + col] = v;
        }
      }
    }
  }
}

// depthwise causal conv(4) + bias + silu; writes fp32 (scans) + bf16 (x_proj)
__global__ __launch_bounds__(256) void conv_silu_k(const float* __restrict__ xz,
                                                   const float* __restrict__ cw,
                                                   const float* __restrict__ cb,
                                                   float* __restrict__ xc,
                                                   unsigned short* __restrict__ xcb) {
  int idx = blockIdx.x * 256 + threadIdx.x;
  int d = idx % DI;
  int m = idx / DI;
  int l = m % SEQ;
  float s = cb[d];
#pragma unroll
  for (int j = 0; j < 4; j++) {
    int tl = l - 3 + j;
    if (tl >= 0) s += xz[(size_t)(m - 3 + j) * (2 * DI) + d] * cw[d * 4 + j];
  }
  float sig = 1.f / (1.f + __expf(-s));
  float r = s * sig;
  xc[idx] = r;
  xcb[idx] = f2bf(r);
}

// chunked scan pass 1
__global__ __launch_bounds__(256) void scan1_k(const float* __restrict__ dt,
                                               const float* __restrict__ xc,
                                               const float* __restrict__ dbc,
                                               const float* __restrict__ A_log_l,
                                               float* __restrict__ cumA,
                                               float* __restrict__ hloc) {
  const int tid = threadIdx.x;
  const int j = blockIdx.x;
  const int cg = blockIdx.y;
  const int b = cg / 6;
  const int d = (cg % 6) * 256 + tid;
  const int c = b * DI + d;

  float Av[DS];
  const float* al = A_log_l + (size_t)d * DS;
#pragma unroll
  for (int s = 0; s < DS; s++) Av[s] = -__expf(al[s]);

  float ap[DS], h[DS];
#pragma unroll
  for (int s = 0; s < DS; s++) { ap[s] = 1.f; h[s] = 0.f; }

  const int t0 = j * CHLEN;
  for (int t = 0; t < CHLEN; t++) {
    int m = b * SEQ + t0 + t;
    float dtv = dt[(size_t)m * DI + d];
    float xv = xc[(size_t)m * DI + d];
    float dtx = dtv * xv;
    const float* bp = dbc + (size_t)m * DBC + NRANK;
#pragma unroll
    for (int s = 0; s < DS; s++) {
      float dA = __expf(dtv * Av[s]);
      h[s] = fmaf(dA, h[s], dtx * bp[s]);
      ap[s] *= dA;
    }
  }
  size_t base = ((size_t)j * (BATCH * DI) + c) * DS;
#pragma unroll
  for (int q = 0; q < 4; q++) {
    *(f32x4*)&cumA[base + q * 4] = (f32x4){ap[q*4], ap[q*4+1], ap[q*4+2], ap[q*4+3]};
    *(f32x4*)&hloc[base + q * 4] = (f32x4){h[q*4], h[q*4+1], h[q*4+2], h[q*4+3]};
  }
}

// pass 2: sequential chunk combine
__global__ __launch_bounds__(256) void scan2_k(const float* __restrict__ cumA,
                                               const float* __restrict__ hloc,
                                               float* __restrict__ hin,
                                               float* __restrict__ states_out) {
  int idx = blockIdx.x * 256 + threadIdx.x;
  const int stride = BATCH * DI * DS;
  float h = 0.f;
  for (int j = 0; j < NCHUNK; j++) {
    hin[(size_t)j * stride + idx] = h;
    h = fmaf(cumA[(size_t)j * stride + idx], h, hloc[(size_t)j * stride + idx]);
  }
  states_out[idx] = h;
}

// pass 3: rerun with true h_in, y = (y + D*xc)*silu(z), bf16 out (out_proj A)
__global__ __launch_bounds__(256) void scan3_k(const float* __restrict__ dt,
                                               const float* __restrict__ xc,
                                               const float* __restrict__ dbc,
                                               const float* __restrict__ xz,
                                               const float* __restrict__ A_log_l,
                                               const float* __restrict__ Dsk,
                                               const float* __restrict__ hin,
                                               unsigned short* __restrict__ y) {
  const int tid = threadIdx.x;
  const int j = blockIdx.x;
  const int cg = blockIdx.y;
  const int b = cg / 6;
  const int d = (cg % 6) * 256 + tid;
  const int c = b * DI + d;

  float Av[DS];
  const float* al = A_log_l + (size_t)d * DS;
#pragma unroll
  for (int s = 0; s < DS; s++) Av[s] = -__expf(al[s]);

  float h[DS];
  size_t base = ((size_t)j * (BATCH * DI) + c) * DS;
#pragma unroll
  for (int s = 0; s < DS; s++) h[s] = hin[base + s];

  float dval = Dsk[d];
  const int t0 = j * CHLEN;
  for (int t = 0; t < CHLEN; t++) {
    int m = b * SEQ + t0 + t;
    float dtv = dt[(size_t)m * DI + d];
    float xv = xc[(size_t)m * DI + d];
    float dtx = dtv * xv;
    const float* bp = dbc + (size_t)m * DBC + NRANK;
    const float* cp = bp + DS;
    float ysum = 0.f;
#pragma unroll
    for (int s = 0; s < DS; s++) {
      float dA = __expf(dtv * Av[s]);
      h[s] = fmaf(dA, h[s], dtx * bp[s]);
      ysum = fmaf(h[s], cp[s], ysum);
    }
    float zv = xz[(size_t)m * (2 * DI) + DI + d];
    float sig = 1.f / (1.f + __expf(-zv));
    y[(size_t)m * DI + d] = f2bf((ysum + dval * xv) * (zv * sig));
  }
}

// LN (w,b) then optionally LN_noaffine + adaln modulate.
// ADA variant also writes bf16 copy (next layer's in_proj A operand).
template<bool ADA>
__global__ __launch_bounds__(256) void ln_k(const float* __restrict__ in,
                                            const float* __restrict__ w,
                                            const float* __restrict__ bb,
                                            const float* __restrict__ ss,
                                            float* __restrict__ out,
                                            unsigned short* __restrict__ outb) {
  __shared__ float red[8];
  const int row = blockIdx.x;
  const int bt = row / SEQ;
  const int tid = threadIdx.x;
  const float* x = in + (size_t)row * DM;
  float v[3];
#pragma unroll
  for (int i = 0; i < 3; i++) v[i] = x[tid + i * 256];
  float s1 = v[0] + v[1] + v[2];
  float s2 = v[0]*v[0] + v[1]*v[1] + v[2]*v[2];
#pragma unroll
  for (int o = 32; o > 0; o >>= 1) { s1 += __shfl_down(s1, o); s2 += __shfl_down(s2, o); }
  int wv = tid >> 6, ln = tid & 63;
  if (ln == 0) { red[wv*2] = s1; red[wv*2+1] = s2; }
  __syncthreads();
  s1 = red[0] + red[2] + red[4] + red[6];
  s2 = red[1] + red[3] + red[5] + red[7];
  float mu = s1 * (1.f / DM);
  float var = s2 * (1.f / DM) - mu * mu;
  float rs = rsqrtf(var + 1e-5f);
  float t[3];
#pragma unroll
  for (int i = 0; i < 3; i++) {
    int c = tid + i * 256;
    t[i] = (v[i] - mu) * rs * w[c] + bb[c];
  }
  if (!ADA) {
#pragma unroll
    for (int i = 0; i < 3; i++) out[(size_t)row * DM + tid + i * 256] = t[i];
    return;
  }
  __syncthreads();
  s1 = t[0] + t[1] + t[2];
  s2 = t[0]*t[0] + t[1]*t[1] + t[2]*t[2];
#pragma unroll
  for (int o = 32; o > 0; o >>= 1) { s1 += __shfl_down(s1, o); s2 += __shfl_down(s2, o); }
  if (ln == 0) { red[wv*2] = s1; red[wv*2+1] = s2; }
  __syncthreads();
  s1 = red[0] + red[2] + red[4] + red[6];
  s2 = red[1] + red[3] + red[5] + red[7];
  float mu2 = s1 * (1.f / DM);
  float var2 = s2 * (1.f / DM) - mu2 * mu2;
  float rs2 = rsqrtf(var2 + 1e-5f);
#pragma unroll
  for (int i = 0; i < 3; i++) {
    int c = tid + i * 256;
    float sc = ss[bt * (2 * DM) + c];
    float sh = ss[bt * (2 * DM) + DM + c];
    float r = (t[i] - mu2) * rs2 * (1.f + sc) + sh;
    out[(size_t)row * DM + c] = r;
    outb[(size_t)row * DM + c] = f2bf(r);
  }
}

// adaln precompute
__global__ __launch_bounds__(256) void adaln_pre_k(const float* __restrict__ cond,
                                                   const float* __restrict__ aw,
                                                   const float* __restrict__ ab,
                                                   float* __restrict__ ss) {
  int idx = blockIdx.x * 256 + threadIdx.x;
  int e = idx % (2 * DM);
  int b = (idx / (2 * DM)) % BATCH;
  int l = idx / (BATCH * 2 * DM);
  const float* c = cond + b * 128;
  const float* wp = aw + ((size_t)l * (2 * DM) + e) * 128;
  float s = ab[l * (2 * DM) + e];
  for (int k = 0; k < 128; k++) s = fmaf(c[k], wp[k], s);
  ss[idx] = s;
}

extern "C" void kernel_launch(void* const* d_in, const int* in_sizes, int n_in,
                              void* d_out, int out_size, void* d_ws, size_t ws_size,
                              hipStream_t stream) {
  const float* x      = (const float*)d_in[0];
  const float* cond   = (const float*)d_in[1];
  const float* in_w   = (const float*)d_in[2];
  const float* conv_w = (const float*)d_in[3];
  const float* conv_b = (const float*)d_in[4];
  const float* xp_w   = (const float*)d_in[5];
  const float* dtp_w  = (const float*)d_in[6];
  const float* dtp_b  = (const float*)d_in[7];
  const float* A_log  = (const float*)d_in[8];
  const float* Dsk    = (const float*)d_in[9];
  const float* out_w  = (const float*)d_in[10];
  const float* norm_w = (const float*)d_in[11];
  const float* norm_b = (const float*)d_in[12];
  const float* ada_w  = (const float*)d_in[13];
  const float* ada_b  = (const float*)d_in[14];
  const float* fn_w   = (const float*)d_in[15];
  const float* fn_b   = (const float*)d_in[16];

  float* out_h = (float*)d_out;
  float* out_states = out_h + (size_t)NTOK * DM;

  float* p = (float*)d_ws;
  float* h_cur = p; p += (size_t)NTOK * DM;
  float* xz    = p; p += (size_t)NTOK * 2 * DI;
  float* xc    = p; p += (size_t)NTOK * DI;
  float* dbc   = p; p += (size_t)NTOK * DBC;
  float* dtb   = p; p += (size_t)NTOK * DI;
  float* yb    = p; p += (size_t)NTOK * DI;
  float* res2  = p; p += (size_t)NTOK * DM;
  float* cumA  = p; p += (size_t)NCHUNK * BATCH * DI * DS;
  float* hloc  = p; p += (size_t)NCHUNK * BATCH * DI * DS;
  float* hin   = p; p += (size_t)NCHUNK * BATCH * DI * DS;
  float* ss    = p; p += (size_t)NL * BATCH * 2 * DM;
  float* xpart = p; p += (size_t)XKS * NTOK * DBC;
  unsigned short* q = (unsigned short*)p;
  unsigned short* in_w_bf  = q; q += (size_t)NL * 2 * DI * DM;
  unsigned short* out_w_bf = q; q += (size_t)NL * DM * DI;
  unsigned short* xp_w_bf  = q; q += (size_t)NL * DBC * DI;
  unsigned short* h_bf     = q; q += (size_t)NTOK * DM;
  unsigned short* xc_bf    = q; q += (size_t)NTOK * DI;
  unsigned short* yb_bf    = (unsigned short*)yb;

  hipMemcpyAsync(h_cur, x, (size_t)NTOK * DM * sizeof(float),
                 hipMemcpyDeviceToDevice, stream);
  adaln_pre_k<<<72, 256, 0, stream>>>(cond, ada_w, ada_b, ss);
  // bf16 preconversions
  f2b_k<<<1536, 256, 0, stream>>>(x, h_bf, NTOK * DM / 4);
  f2b_k<<<2048, 256, 0, stream>>>(in_w, in_w_bf, NL * 2 * DI * DM / 4);
  f2b_k<<<2048, 256, 0, stream>>>(out_w, out_w_bf, NL * DM * DI / 4);
  f2b_k<<<720, 256, 0, stream>>>(xp_w, xp_w_bf, NL * DBC * DI / 4);

  for (int l = 0; l < NL; l++) {
    // in_proj: (2048x768) x (3072x768)^T -> xz
    bt128b_k<0><<<dim3(24, 16), 256, 0, stream>>>(
        h_bf, DM, in_w_bf + (size_t)l * 2 * DI * DM, DM, xz, 2 * DI,
        DM, nullptr);
    // conv + silu
    conv_silu_k<<<(NTOK * DI) / 256, 256, 0, stream>>>(
        xz, conv_w + (size_t)l * DI * 4, conv_b + (size_t)l * DI, xc, xc_bf);
    // x_proj split-K
    xp_k<<<dim3(XKS, NTOK / 64), 256, 0, stream>>>(
        xc_bf, xp_w_bf + (size_t)l * DBC * DI, xpart);
    xp_reduce_k<<<NTOK * DBC / 4 / 256, 256, 0, stream>>>(xpart, dbc);
    // dt_proj + softplus
    gemm_bt_k<1><<<dim3(24, 32), 256, 0, stream>>>(
        dbc, DBC, dtp_w + (size_t)l * DI * NRANK, NRANK, dtb, DI,
        NTOK, DI, NRANK, dtp_b + (size_t)l * DI);
    // chunked scan
    scan1_k<<<dim3(NCHUNK, 12), 256, 0, stream>>>(
        dtb, xc, dbc, A_log + (size_t)l * DI * DS, cumA, hloc);
    scan2_k<<<192, 256, 0, stream>>>(
        cumA, hloc, hin, out_states + (size_t)l * BATCH * DI * DS);
    scan3_k<<<dim3(NCHUNK, 12), 256, 0, stream>>>(
        dtb, xc, dbc, xz, A_log + (size_t)l * DI * DS, Dsk + (size_t)l * DI,
        hin, yb_bf);
    // out_proj + residual
    bt128b_k<2><<<dim3(6, 16), 256, 0, stream>>>(
        yb_bf, DI, out_w_bf + (size_t)l * DM * DI, DI, res2, DM,
        DI, h_cur);
    // LN + adaln modulate -> h_cur (fp32) + h_bf (bf16)
    ln_k<true><<<NTOK, 256, 0, stream>>>(
        res2, norm_w + (size_t)l * DM, norm_b + (size_t)l * DM,
        ss + (size_t)l * BATCH * 2 * DM, h_cur, h_bf);
  }
  ln_k<false><<<NTOK, 256, 0, stream>>>(h_cur, fn_w, fn_b, nullptr, out_h, nullptr);
}

// Round 5
// 1018.511 us; speedup vs baseline: 1.4442x; 1.0806x over previous
//
#include <hip/hip_runtime.h>
#include <hip/hip_bf16.h>

#define NL 6
#define DM 768
#define DI 1536
#define DS 16
#define NRANK 48
#define DBC 80
#define BATCH 2
#define SEQ 1024
#define NTOK (BATCH*SEQ)
#define NCHUNK 16
#define CHLEN 64
#define XKS 8
#define XKC (DI/XKS)

typedef __attribute__((ext_vector_type(8))) short short8;
typedef __attribute__((ext_vector_type(4))) float f32x4;
typedef __attribute__((ext_vector_type(4))) unsigned short ushort4v;

__device__ inline unsigned short f2bf(float f) {
  union { float f; unsigned u; } x; x.f = f;
  unsigned r = x.u + 0x7FFF + ((x.u >> 16) & 1);
  return (unsigned short)(r >> 16);
}

__device__ inline void gl_lds16(const unsigned short* g, unsigned short* l) {
  __builtin_amdgcn_global_load_lds(
      (const __attribute__((address_space(1))) unsigned int*)(g),
      (__attribute__((address_space(3))) unsigned int*)(l),
      16, 0, 0);
}

// fp32 -> bf16 bulk convert
__global__ __launch_bounds__(256) void f2b_k(const float* __restrict__ src,
                                             unsigned short* __restrict__ dst,
                                             int n4) {
  for (int i = blockIdx.x * 256 + threadIdx.x; i < n4; i += gridDim.x * 256) {
    f32x4 v = ((const f32x4*)src)[i];
    union { ushort4v u4; __hip_bfloat162 h[2]; } u;
    float2 p;
    p.x = v[0]; p.y = v[1]; u.h[0] = __float22bfloat162_rn(p);
    p.x = v[2]; p.y = v[3]; u.h[1] = __float22bfloat162_rn(p);
    ((ushort4v*)dst)[i] = u.u4;
  }
}

// pad dtp_w [NL][1536][48] fp32 -> [NL][1536][64] bf16 (cols 48..63 zero)
__global__ __launch_bounds__(256) void dtw_pad_k(const float* __restrict__ w,
                                                 unsigned short* __restrict__ wb) {
  int idx = blockIdx.x * 256 + threadIdx.x;  // NL*1536*64
  if (idx >= NL * 1536 * 64) return;
  int col = idx & 63;
  int row = idx >> 6;  // NL*1536
  wb[idx] = (col < NRANK) ? f2bf(w[(size_t)row * NRANK + col]) : (unsigned short)0;
}

// ---------------------------------------------------------------------------
// 128x128-tile bf16 GEMM, global_load_lds staging, double-buffered LDS.
// C[M,N] = A[M,K] * W[N,K]^T, fp32 out. EPI 0: plain. EPI 2: + resid.
// ---------------------------------------------------------------------------
template<int EPI>
__global__ __launch_bounds__(256) void bt128b_k(
    const unsigned short* __restrict__ A, int lda,
    const unsigned short* __restrict__ W, int ldw,
    float* __restrict__ C, int ldc,
    int K,
    const float* __restrict__ resid) {
  __shared__ __align__(16) unsigned short As[2][128 * 32];
  __shared__ __align__(16) unsigned short Ws[2][128 * 32];
  const int tid = threadIdx.x;
  const int bm = blockIdx.y * 128;
  const int bn = blockIdx.x * 128;
  const int lane = tid & 63;
  const int wv = tid >> 6;
  const int wm = (wv >> 1) * 64;
  const int wn = (wv & 1) * 64;
  const int fr = lane & 15;
  const int fs = lane >> 4;

  const int r0 = tid >> 2;
  const int s0 = (tid & 3) ^ (r0 & 3);

  const unsigned short* gA0 = A + (size_t)(bm + r0) * lda + s0 * 8;
  const unsigned short* gA1 = A + (size_t)(bm + r0 + 64) * lda + s0 * 8;
  const unsigned short* gW0 = W + (size_t)(bn + r0) * ldw + s0 * 8;
  const unsigned short* gW1 = W + (size_t)(bn + r0 + 64) * ldw + s0 * 8;

  f32x4 acc[4][4];
#pragma unroll
  for (int i = 0; i < 4; i++)
#pragma unroll
    for (int j = 0; j < 4; j++) acc[i][j] = (f32x4){0.f, 0.f, 0.f, 0.f};

  gl_lds16(gA0, &As[0][0] + tid * 8);
  gl_lds16(gA1, &As[0][2048] + tid * 8);
  gl_lds16(gW0, &Ws[0][0] + tid * 8);
  gl_lds16(gW1, &Ws[0][2048] + tid * 8);
  __syncthreads();

  const int nk = K >> 5;
  int buf = 0;
  for (int kk = 0; kk < nk; kk++) {
    if (kk + 1 < nk) {
      const int k0 = (kk + 1) * 32;
      gl_lds16(gA0 + k0, &As[buf ^ 1][0] + tid * 8);
      gl_lds16(gA1 + k0, &As[buf ^ 1][2048] + tid * 8);
      gl_lds16(gW0 + k0, &Ws[buf ^ 1][0] + tid * 8);
      gl_lds16(gW1 + k0, &Ws[buf ^ 1][2048] + tid * 8);
    }

    short8 af[4], bf[4];
#pragma unroll
    for (int i = 0; i < 4; i++) {
      int rowa = wm + i * 16 + fr;
      af[i] = *(const short8*)&As[buf][rowa * 32 + ((fs ^ (rowa & 3)) * 8)];
      int rowb = wn + i * 16 + fr;
      bf[i] = *(const short8*)&Ws[buf][rowb * 32 + ((fs ^ (rowb & 3)) * 8)];
    }
#pragma unroll
    for (int i = 0; i < 4; i++)
#pragma unroll
      for (int j = 0; j < 4; j++)
        acc[i][j] = __builtin_amdgcn_mfma_f32_16x16x32_bf16(af[i], bf[j], acc[i][j], 0, 0, 0);

    __syncthreads();
    buf ^= 1;
  }

#pragma unroll
  for (int i = 0; i < 4; i++) {
#pragma unroll
    for (int j = 0; j < 4; j++) {
#pragma unroll
      for (int r = 0; r < 4; r++) {
        int row = bm + wm + i * 16 + fs * 4 + r;
        int col = bn + wn + j * 16 + fr;
        float v = acc[i][j][r];
        if (EPI == 2) v += resid[(size_t)row * ldc + col];
        C[(size_t)row * ldc + col] = v;
      }
    }
  }
}

// ---------------------------------------------------------------------------
// 64x64-tile bf16 GEMM, global_load_lds + dbuf.
// EPI 1: softplus(v + bias[col]). EPI 2: v + resid.
// ---------------------------------------------------------------------------
template<int EPI>
__global__ __launch_bounds__(256) void bt64_k(
    const unsigned short* __restrict__ A, int lda,
    const unsigned short* __restrict__ W, int ldw,
    float* __restrict__ C, int ldc,
    int K,
    const float* __restrict__ bias,
    const float* __restrict__ resid) {
  __shared__ __align__(16) unsigned short As[2][64 * 32];
  __shared__ __align__(16) unsigned short Ws[2][64 * 32];
  const int tid = threadIdx.x;
  const int bm = blockIdx.y * 64;
  const int bn = blockIdx.x * 64;
  const int lane = tid & 63;
  const int wv = tid >> 6;
  const int wm = (wv >> 1) * 32;
  const int wn = (wv & 1) * 32;
  const int fr = lane & 15;
  const int fs = lane >> 4;

  const int r0 = tid >> 2;
  const int s0 = (tid & 3) ^ (r0 & 3);

  const unsigned short* gA = A + (size_t)(bm + r0) * lda + s0 * 8;
  const unsigned short* gW = W + (size_t)(bn + r0) * ldw + s0 * 8;

  f32x4 acc[2][2];
#pragma unroll
  for (int i = 0; i < 2; i++)
#pragma unroll
    for (int j = 0; j < 2; j++) acc[i][j] = (f32x4){0.f, 0.f, 0.f, 0.f};

  gl_lds16(gA, &As[0][0] + tid * 8);
  gl_lds16(gW, &Ws[0][0] + tid * 8);
  __syncthreads();

  const int nk = K >> 5;
  int buf = 0;
  for (int kk = 0; kk < nk; kk++) {
    if (kk + 1 < nk) {
      const int k0 = (kk + 1) * 32;
      gl_lds16(gA + k0, &As[buf ^ 1][0] + tid * 8);
      gl_lds16(gW + k0, &Ws[buf ^ 1][0] + tid * 8);
    }

    short8 af[2], bf[2];
#pragma unroll
    for (int i = 0; i < 2; i++) {
      int rowa = wm + i * 16 + fr;
      af[i] = *(const short8*)&As[buf][rowa * 32 + ((fs ^ (rowa & 3)) * 8)];
      int rowb = wn + i * 16 + fr;
      bf[i] = *(const short8*)&Ws[buf][rowb * 32 + ((fs ^ (rowb & 3)) * 8)];
    }
#pragma unroll
    for (int i = 0; i < 2; i++)
#pragma unroll
      for (int j = 0; j < 2; j++)
        acc[i][j] = __builtin_amdgcn_mfma_f32_16x16x32_bf16(af[i], bf[j], acc[i][j], 0, 0, 0);

    __syncthreads();
    buf ^= 1;
  }

#pragma unroll
  for (int i = 0; i < 2; i++) {
#pragma unroll
    for (int j = 0; j < 2; j++) {
#pragma unroll
      for (int r = 0; r < 4; r++) {
        int row = bm + wm + i * 16 + fs * 4 + r;
        int col = bn + wn + j * 16 + fr;
        float v = acc[i][j][r];
        if (EPI == 1) {
          float xv = v + bias[col];
          v = (xv > 20.f) ? xv : log1pf(__expf(xv));
        }
        if (EPI == 2) v += resid[(size_t)row * ldc + col];
        C[(size_t)row * ldc + col] = v;
      }
    }
  }
}

// ---------------------------------------------------------------------------
// x_proj split-K, bf16: C[2048,80] = A[2048,1536] * W[80,1536]^T
// ---------------------------------------------------------------------------
__global__ __launch_bounds__(256) void xp_k(
    const unsigned short* __restrict__ A,
    const unsigned short* __restrict__ W,
    float* __restrict__ part) {
  __shared__ __align__(16) unsigned short As[64][40];
  __shared__ __align__(16) unsigned short Ws[80][40];
  const int tid = threadIdx.x;
  const int ks = blockIdx.x;
  const int bm = blockIdx.y * 64;
  const int lane = tid & 63;
  const int wv = tid >> 6;
  const int fr = lane & 15;
  const int fs = lane >> 4;
  const int fk = fs * 8;

  const int ar = tid >> 2;
  const int ac = (tid & 3) * 8;
  const int k0base = ks * XKC;

  const unsigned short* gA  = A + (size_t)(bm + ar) * DI + k0base + ac;
  const unsigned short* gW0 = W + (size_t)ar * DI + k0base + ac;
  const unsigned short* gW1 = W + (size_t)(64 + ar) * DI + k0base + ac;

  f32x4 acc[5];
#pragma unroll
  for (int n = 0; n < 5; n++) acc[n] = (f32x4){0.f, 0.f, 0.f, 0.f};

  short8 aA, w0A, w1A;
  aA = *(const short8*)(gA);
  w0A = *(const short8*)(gW0);
  if (tid < 64) w1A = *(const short8*)(gW1);

  const int nk = XKC / 32;  // 6
  for (int kk = 0; kk < nk; kk++) {
    __syncthreads();
    *(short8*)&As[ar][ac] = aA;
    *(short8*)&Ws[ar][ac] = w0A;
    if (tid < 64) *(short8*)&Ws[64 + ar][ac] = w1A;
    __syncthreads();

    if (kk + 1 < nk) {
      const int k0 = (kk + 1) * 32;
      aA = *(const short8*)(gA + k0);
      w0A = *(const short8*)(gW0 + k0);
      if (tid < 64) w1A = *(const short8*)(gW1 + k0);
    }

    short8 af = *(const short8*)&As[wv * 16 + fr][fk];
#pragma unroll
    for (int n = 0; n < 5; n++) {
      short8 bf = *(const short8*)&Ws[n * 16 + fr][fk];
      acc[n] = __builtin_amdgcn_mfma_f32_16x16x32_bf16(af, bf, acc[n], 0, 0, 0);
    }
  }

#pragma unroll
  for (int n = 0; n < 5; n++) {
#pragma unroll
    for (int r = 0; r < 4; r++) {
      int row = bm + wv * 16 + fs * 4 + r;
      part[((size_t)ks * NTOK + row) * DBC + n * 16 + fr] = acc[n][r];
    }
  }
}

// sum XKS partials -> dbc (fp32); also write bf16 zero-padded dt-input [m][64]
__global__ __launch_bounds__(256) void xp_reduce_k(const float* __restrict__ part,
                                                   float* __restrict__ dbc,
                                                   unsigned short* __restrict__ dtA) {
  int i = blockIdx.x * 256 + threadIdx.x;  // NTOK*DBC/4 = 40960
  const f32x4* p4 = (const f32x4*)part;
  const int stride4 = NTOK * DBC / 4;
  f32x4 s = p4[i];
#pragma unroll
  for (int ks = 1; ks < XKS; ks++) {
    f32x4 v = p4[(size_t)ks * stride4 + i];
    s[0] += v[0]; s[1] += v[1]; s[2] += v[2]; s[3] += v[3];
  }
  ((f32x4*)dbc)[i] = s;
  int c4 = (i * 4) % DBC;
  int m = (i * 4) / DBC;
  if (c4 < 64) {
    union { ushort4v u4; __hip_bfloat162 h[2]; } u;
    if (c4 < NRANK) {
      float2 p;
      p.x = s[0]; p.y = s[1]; u.h[0] = __float22bfloat162_rn(p);
      p.x = s[2]; p.y = s[3]; u.h[1] = __float22bfloat162_rn(p);
    } else {
      u.u4 = (ushort4v){0, 0, 0, 0};
    }
    *(ushort4v*)&dtA[(size_t)m * 64 + c4] = u.u4;
  }
}

// depthwise causal conv(4) + bias + silu, register-carry (reads xz once)
__global__ __launch_bounds__(256) void conv_silu_k(const float* __restrict__ xz,
                                                   const float* __restrict__ cw,
                                                   const float* __restrict__ cb,
                                                   float* __restrict__ xc,
                                                   unsigned short* __restrict__ xcb) {
  const int d = blockIdx.x * 256 + threadIdx.x;
  const int l0 = blockIdx.y * 16;
  const int b = blockIdx.z;
  const size_t mbase = (size_t)b * SEQ;
  const float w0 = cw[d * 4 + 0], w1 = cw[d * 4 + 1];
  const float w2 = cw[d * 4 + 2], w3 = cw[d * 4 + 3];
  const float bias = cb[d];
  float c3 = (l0 >= 3) ? xz[(mbase + l0 - 3) * (2 * DI) + d] : 0.f;
  float c2 = (l0 >= 2) ? xz[(mbase + l0 - 2) * (2 * DI) + d] : 0.f;
  float c1 = (l0 >= 1) ? xz[(mbase + l0 - 1) * (2 * DI) + d] : 0.f;
#pragma unroll
  for (int t = 0; t < 16; t++) {
    const int l = l0 + t;
    float cur = xz[(mbase + l) * (2 * DI) + d];
    float s = bias + w0 * c3 + w1 * c2 + w2 * c1 + w3 * cur;
    float sig = 1.f / (1.f + __expf(-s));
    float r = s * sig;
    size_t idx = (mbase + l) * DI + d;
    xc[idx] = r;
    xcb[idx] = f2bf(r);
    c3 = c2; c2 = c1; c1 = cur;
  }
}

// chunked scan pass 1 (exp-chain fast path when A_log = log(1..16))
__global__ __launch_bounds__(256) void scan1_k(const float* __restrict__ dt,
                                               const float* __restrict__ xc,
                                               const float* __restrict__ dbc,
                                               const float* __restrict__ A_log_l,
                                               float* __restrict__ cumA,
                                               float* __restrict__ hloc) {
  const int tid = threadIdx.x;
  const int j = blockIdx.x;
  const int cg = blockIdx.y;
  const int b = cg / 6;
  const int d = (cg % 6) * 256 + tid;
  const int c = b * DI + d;

  float Av[DS];
  const float* al = A_log_l + (size_t)d * DS;
#pragma unroll
  for (int s = 0; s < DS; s++) Av[s] = -__expf(al[s]);
  const float Av0 = Av[0];
  bool fast = true;
#pragma unroll
  for (int s = 0; s < DS; s++)
    fast = fast && (fabsf(Av[s] - (s + 1) * Av0) <= 1e-4f * (s + 1));

  float ap[DS], h[DS];
#pragma unroll
  for (int s = 0; s < DS; s++) { ap[s] = 1.f; h[s] = 0.f; }

  const int t0 = j * CHLEN;
  if (fast) {
    float p = 1.f;
    for (int t = 0; t < CHLEN; t++) {
      int m = b * SEQ + t0 + t;
      float dtv = dt[(size_t)m * DI + d];
      float xv = xc[(size_t)m * DI + d];
      float dtx = dtv * xv;
      const float* bp = dbc + (size_t)m * DBC + NRANK;
      float e1 = __expf(dtv * Av0);
      float dA = e1;
      h[0] = fmaf(dA, h[0], dtx * bp[0]);
#pragma unroll
      for (int s = 1; s < DS; s++) {
        dA *= e1;
        h[s] = fmaf(dA, h[s], dtx * bp[s]);
      }
      p *= e1;
    }
    float q = p;
    ap[0] = q;
#pragma unroll
    for (int s = 1; s < DS; s++) { q *= p; ap[s] = q; }
  } else {
    for (int t = 0; t < CHLEN; t++) {
      int m = b * SEQ + t0 + t;
      float dtv = dt[(size_t)m * DI + d];
      float xv = xc[(size_t)m * DI + d];
      float dtx = dtv * xv;
      const float* bp = dbc + (size_t)m * DBC + NRANK;
#pragma unroll
      for (int s = 0; s < DS; s++) {
        float dA = __expf(dtv * Av[s]);
        h[s] = fmaf(dA, h[s], dtx * bp[s]);
        ap[s] *= dA;
      }
    }
  }
  size_t base = ((size_t)j * (BATCH * DI) + c) * DS;
#pragma unroll
  for (int q = 0; q < 4; q++) {
    *(f32x4*)&cumA[base + q * 4] = (f32x4){ap[q*4], ap[q*4+1], ap[q*4+2], ap[q*4+3]};
    *(f32x4*)&hloc[base + q * 4] = (f32x4){h[q*4], h[q*4+1], h[q*4+2], h[q*4+3]};
  }
}

// pass 2: sequential chunk combine
__global__ __launch_bounds__(256) void scan2_k(const float* __restrict__ cumA,
                                               const float* __restrict__ hloc,
                                               float* __restrict__ hin,
                                               float* __restrict__ states_out) {
  int idx = blockIdx.x * 256 + threadIdx.x;
  const int stride = BATCH * DI * DS;
  float h = 0.f;
  for (int j = 0; j < NCHUNK; j++) {
    hin[(size_t)j * stride + idx] = h;
    h = fmaf(cumA[(size_t)j * stride + idx], h, hloc[(size_t)j * stride + idx]);
  }
  states_out[idx] = h;
}

// pass 3: rerun with true h_in, y = (y + D*xc)*silu(z), bf16 out
__global__ __launch_bounds__(256) void scan3_k(const float* __restrict__ dt,
                                               const float* __restrict__ xc,
                                               const float* __restrict__ dbc,
                                               const float* __restrict__ xz,
                                               const float* __restrict__ A_log_l,
                                               const float* __restrict__ Dsk,
                                               const float* __restrict__ hin,
                                               unsigned short* __restrict__ y) {
  const int tid = threadIdx.x;
  const int j = blockIdx.x;
  const int cg = blockIdx.y;
  const int b = cg / 6;
  const int d = (cg % 6) * 256 + tid;
  const int c = b * DI + d;

  float Av[DS];
  const float* al = A_log_l + (size_t)d * DS;
#pragma unroll
  for (int s = 0; s < DS; s++) Av[s] = -__expf(al[s]);
  const float Av0 = Av[0];
  bool fast = true;
#pragma unroll
  for (int s = 0; s < DS; s++)
    fast = fast && (fabsf(Av[s] - (s + 1) * Av0) <= 1e-4f * (s + 1));

  float h[DS];
  size_t base = ((size_t)j * (BATCH * DI) + c) * DS;
#pragma unroll
  for (int s = 0; s < DS; s++) h[s] = hin[base + s];

  float dval = Dsk[d];
  const int t0 = j * CHLEN;
  for (int t = 0; t < CHLEN; t++) {
    int m = b * SEQ + t0 + t;
    float dtv = dt[(size_t)m * DI + d];
    float xv = xc[(size_t)m * DI + d];
    float dtx = dtv * xv;
    const float* bp = dbc + (size_t)m * DBC + NRANK;
    const float* cp = bp + DS;
    float ysum = 0.f;
    if (fast) {
      float e1 = __expf(dtv * Av0);
      float dA = e1;
      h[0] = fmaf(dA, h[0], dtx * bp[0]);
      ysum = fmaf(h[0], cp[0], ysum);
#pragma unroll
      for (int s = 1; s < DS; s++) {
        dA *= e1;
        h[s] = fmaf(dA, h[s], dtx * bp[s]);
        ysum = fmaf(h[s], cp[s], ysum);
      }
    } else {
#pragma unroll
      for (int s = 0; s < DS; s++) {
        float dA = __expf(dtv * Av[s]);
        h[s] = fmaf(dA, h[s], dtx * bp[s]);
        ysum = fmaf(h[s], cp[s], ysum);
      }
    }
    float zv = xz[(size_t)m * (2 * DI) + DI + d];
    float sig = 1.f / (1.f + __expf(-zv));
    y[(size_t)m * DI + d] = f2bf((ysum + dval * xv) * (zv * sig));
  }
}

// LN (w,b) then optionally LN_noaffine + adaln modulate
template<bool ADA>
__global__ __launch_bounds__(256) void ln_k(const float* __restrict__ in,
                                            const float* __restrict__ w,
                                            const float* __restrict__ bb,
                                            const float* __restrict__ ss,
                                            float* __restrict__ out,
                                            unsigned short* __restrict__ outb) {
  __shared__ float red[8];
  const int row = blockIdx.x;
  const int bt = row / SEQ;
  const int tid = threadIdx.x;
  const float* x = in + (size_t)row * DM;
  float v[3];
#pragma unroll
  for (int i = 0; i < 3; i++) v[i] = x[tid + i * 256];
  float s1 = v[0] + v[1] + v[2];
  float s2 = v[0]*v[0] + v[1]*v[1] + v[2]*v[2];
#pragma unroll
  for (int o = 32; o > 0; o >>= 1) { s1 += __shfl_down(s1, o); s2 += __shfl_down(s2, o); }
  int wv = tid >> 6, ln = tid & 63;
  if (ln == 0) { red[wv*2] = s1; red[wv*2+1] = s2; }
  __syncthreads();
  s1 = red[0] + red[2] + red[4] + red[6];
  s2 = red[1] + red[3] + red[5] + red[7];
  float mu = s1 * (1.f / DM);
  float var = s2 * (1.f / DM) - mu * mu;
  float rs = rsqrtf(var + 1e-5f);
  float t[3];
#pragma unroll
  for (int i = 0; i < 3; i++) {
    int c = tid + i * 256;
    t[i] = (v[i] - mu) * rs * w[c] + bb[c];
  }
  if (!ADA) {
#pragma unroll
    for (int i = 0; i < 3; i++) out[(size_t)row * DM + tid + i * 256] = t[i];
    return;
  }
  __syncthreads();
  s1 = t[0] + t[1] + t[2];
  s2 = t[0]*t[0] + t[1]*t[1] + t[2]*t[2];
#pragma unroll
  for (int o = 32; o > 0; o >>= 1) { s1 += __shfl_down(s1, o); s2 += __shfl_down(s2, o); }
  if (ln == 0) { red[wv*2] = s1; red[wv*2+1] = s2; }
  __syncthreads();
  s1 = red[0] + red[2] + red[4] + red[6];
  s2 = red[1] + red[3] + red[5] + red[7];
  float mu2 = s1 * (1.f / DM);
  float var2 = s2 * (1.f / DM) - mu2 * mu2;
  float rs2 = rsqrtf(var2 + 1e-5f);
#pragma unroll
  for (int i = 0; i < 3; i++) {
    int c = tid + i * 256;
    float sc = ss[bt * (2 * DM) + c];
    float sh = ss[bt * (2 * DM) + DM + c];
    float r = (t[i] - mu2) * rs2 * (1.f + sc) + sh;
    out[(size_t)row * DM + c] = r;
    outb[(size_t)row * DM + c] = f2bf(r);
  }
}

// adaln precompute
__global__ __launch_bounds__(256) void adaln_pre_k(const float* __restrict__ cond,
                                                   const float* __restrict__ aw,
                                                   const float* __restrict__ ab,
                                                   float* __restrict__ ss) {
  int idx = blockIdx.x * 256 + threadIdx.x;
  int e = idx % (2 * DM);
  int b = (idx / (2 * DM)) % BATCH;
  int l = idx / (BATCH * 2 * DM);
  const float* c = cond + b * 128;
  const float* wp = aw + ((size_t)l * (2 * DM) + e) * 128;
  float s = ab[l * (2 * DM) + e];
  for (int k = 0; k < 128; k++) s = fmaf(c[k], wp[k], s);
  ss[idx] = s;
}

extern "C" void kernel_launch(void* const* d_in, const int* in_sizes, int n_in,
                              void* d_out, int out_size, void* d_ws, size_t ws_size,
                              hipStream_t stream) {
  const float* x      = (const float*)d_in[0];
  const float* cond   = (const float*)d_in[1];
  const float* in_w   = (const float*)d_in[2];
  const float* conv_w = (const float*)d_in[3];
  const float* conv_b = (const float*)d_in[4];
  const float* xp_w   = (const float*)d_in[5];
  const float* dtp_w  = (const float*)d_in[6];
  const float* dtp_b  = (const float*)d_in[7];
  const float* A_log  = (const float*)d_in[8];
  const float* Dsk    = (const float*)d_in[9];
  const float* out_w  = (const float*)d_in[10];
  const float* norm_w = (const float*)d_in[11];
  const float* norm_b = (const float*)d_in[12];
  const float* ada_w  = (const float*)d_in[13];
  const float* ada_b  = (const float*)d_in[14];
  const float* fn_w   = (const float*)d_in[15];
  const float* fn_b   = (const float*)d_in[16];

  float* out_h = (float*)d_out;
  float* out_states = out_h + (size_t)NTOK * DM;

  float* p = (float*)d_ws;
  float* h_cur = p; p += (size_t)NTOK * DM;
  float* xz    = p; p += (size_t)NTOK * 2 * DI;
  float* xc    = p; p += (size_t)NTOK * DI;
  float* dbc   = p; p += (size_t)NTOK * DBC;
  float* dtb   = p; p += (size_t)NTOK * DI;
  float* yb    = p; p += (size_t)NTOK * DI;
  float* res2  = p; p += (size_t)NTOK * DM;
  float* cumA  = p; p += (size_t)NCHUNK * BATCH * DI * DS;
  float* hloc  = p; p += (size_t)NCHUNK * BATCH * DI * DS;
  float* hin   = p; p += (size_t)NCHUNK * BATCH * DI * DS;
  float* ss    = p; p += (size_t)NL * BATCH * 2 * DM;
  float* xpart = p; p += (size_t)XKS * NTOK * DBC;
  unsigned short* q = (unsigned short*)p;
  unsigned short* in_w_bf  = q; q += (size_t)NL * 2 * DI * DM;
  unsigned short* out_w_bf = q; q += (size_t)NL * DM * DI;
  unsigned short* xp_w_bf  = q; q += (size_t)NL * DBC * DI;
  unsigned short* dtw_bf   = q; q += (size_t)NL * DI * 64;
  unsigned short* h_bf     = q; q += (size_t)NTOK * DM;
  unsigned short* xc_bf    = q; q += (size_t)NTOK * DI;
  unsigned short* dtA_bf   = q; q += (size_t)NTOK * 64;
  unsigned short* yb_bf    = (unsigned short*)yb;

  hipMemcpyAsync(h_cur, x, (size_t)NTOK * DM * sizeof(float),
                 hipMemcpyDeviceToDevice, stream);
  adaln_pre_k<<<72, 256, 0, stream>>>(cond, ada_w, ada_b, ss);
  f2b_k<<<1536, 256, 0, stream>>>(x, h_bf, NTOK * DM / 4);
  f2b_k<<<2048, 256, 0, stream>>>(in_w, in_w_bf, NL * 2 * DI * DM / 4);
  f2b_k<<<2048, 256, 0, stream>>>(out_w, out_w_bf, NL * DM * DI / 4);
  f2b_k<<<720, 256, 0, stream>>>(xp_w, xp_w_bf, NL * DBC * DI / 4);
  dtw_pad_k<<<(NL * 1536 * 64 + 255) / 256, 256, 0, stream>>>(dtp_w, dtw_bf);

  for (int l = 0; l < NL; l++) {
    // in_proj: (2048x768) x (3072x768)^T -> xz
    bt128b_k<0><<<dim3(24, 16), 256, 0, stream>>>(
        h_bf, DM, in_w_bf + (size_t)l * 2 * DI * DM, DM, xz, 2 * DI,
        DM, nullptr);
    // conv + silu (register-carry)
    conv_silu_k<<<dim3(DI / 256, SEQ / 16, BATCH), 256, 0, stream>>>(
        xz, conv_w + (size_t)l * DI * 4, conv_b + (size_t)l * DI, xc, xc_bf);
    // x_proj split-K
    xp_k<<<dim3(XKS, NTOK / 64), 256, 0, stream>>>(
        xc_bf, xp_w_bf + (size_t)l * DBC * DI, xpart);
    xp_reduce_k<<<NTOK * DBC / 4 / 256, 256, 0, stream>>>(xpart, dbc, dtA_bf);
    // dt_proj + softplus: (2048x64pad) x (1536x64pad)^T -> dtb
    bt64_k<1><<<dim3(DI / 64, NTOK / 64), 256, 0, stream>>>(
        dtA_bf, 64, dtw_bf + (size_t)l * DI * 64, 64, dtb, DI,
        64, dtp_b + (size_t)l * DI, nullptr);
    // chunked scan
    scan1_k<<<dim3(NCHUNK, 12), 256, 0, stream>>>(
        dtb, xc, dbc, A_log + (size_t)l * DI * DS, cumA, hloc);
    scan2_k<<<192, 256, 0, stream>>>(
        cumA, hloc, hin, out_states + (size_t)l * BATCH * DI * DS);
    scan3_k<<<dim3(NCHUNK, 12), 256, 0, stream>>>(
        dtb, xc, dbc, xz, A_log + (size_t)l * DI * DS, Dsk + (size_t)l * DI,
        hin, yb_bf);
    // out_proj + residual: (2048x1536) x (768x1536)^T -> res2
    bt64_k<2><<<dim3(DM / 64, NTOK / 64), 256, 0, stream>>>(
        yb_bf, DI, out_w_bf + (size_t)l * DM * DI, DI, res2, DM,
        DI, nullptr, h_cur);
    // LN + adaln modulate -> h_cur (fp32) + h_bf (bf16)
    ln_k<true><<<NTOK, 256, 0, stream>>>(
        res2, norm_w + (size_t)l * DM, norm_b + (size_t)l * DM,
        ss + (size_t)l * BATCH * 2 * DM, h_cur, h_bf);
  }
  ln_k<false><<<NTOK, 256, 0, stream>>>(h_cur, fn_w, fn_b, nullptr, out_h, nullptr);
}

// Round 6
// 914.169 us; speedup vs baseline: 1.6091x; 1.1141x over previous
//
#include <hip/hip_runtime.h>
#include <hip/hip_bf16.h>

#define NL 6
#define DM 768
#define DI 1536
#define DS 16
#define NRANK 48
#define DBC 80
#define BATCH 2
#define SEQ 1024
#define NTOK (BATCH*SEQ)
#define NCHUNK 64
#define CHLEN 16
#define XKS 8
#define XKC (DI/XKS)

typedef __attribute__((ext_vector_type(8))) short short8;
typedef __attribute__((ext_vector_type(4))) float f32x4;
typedef __attribute__((ext_vector_type(4))) unsigned short ushort4v;

__device__ inline unsigned short f2bf(float f) {
  union { float f; unsigned u; } x; x.f = f;
  unsigned r = x.u + 0x7FFF + ((x.u >> 16) & 1);
  return (unsigned short)(r >> 16);
}

__device__ inline void gl_lds16(const unsigned short* g, unsigned short* l) {
  __builtin_amdgcn_global_load_lds(
      (const __attribute__((address_space(1))) unsigned int*)(g),
      (__attribute__((address_space(3))) unsigned int*)(l),
      16, 0, 0);
}

// fp32 -> bf16 bulk convert
__global__ __launch_bounds__(256) void f2b_k(const float* __restrict__ src,
                                             unsigned short* __restrict__ dst,
                                             int n4) {
  for (int i = blockIdx.x * 256 + threadIdx.x; i < n4; i += gridDim.x * 256) {
    f32x4 v = ((const f32x4*)src)[i];
    union { ushort4v u4; __hip_bfloat162 h[2]; } u;
    float2 p;
    p.x = v[0]; p.y = v[1]; u.h[0] = __float22bfloat162_rn(p);
    p.x = v[2]; p.y = v[3]; u.h[1] = __float22bfloat162_rn(p);
    ((ushort4v*)dst)[i] = u.u4;
  }
}

// pad dtp_w [NL][1536][48] fp32 -> [NL][1536][64] bf16
__global__ __launch_bounds__(256) void dtw_pad_k(const float* __restrict__ w,
                                                 unsigned short* __restrict__ wb) {
  int idx = blockIdx.x * 256 + threadIdx.x;
  if (idx >= NL * 1536 * 64) return;
  int col = idx & 63;
  int row = idx >> 6;
  wb[idx] = (col < NRANK) ? f2bf(w[(size_t)row * NRANK + col]) : (unsigned short)0;
}

// negA[l][d][s] = -exp(A_log[l][d][s])
__global__ __launch_bounds__(256) void negA_k(const float* __restrict__ al,
                                              float* __restrict__ na) {
  int idx = blockIdx.x * 256 + threadIdx.x;
  if (idx < NL * DI * DS) na[idx] = -__expf(al[idx]);
}

// ---------------------------------------------------------------------------
// 128x128-tile bf16 GEMM, global_load_lds + double buffer.
// ---------------------------------------------------------------------------
template<int EPI>
__global__ __launch_bounds__(256) void bt128b_k(
    const unsigned short* __restrict__ A, int lda,
    const unsigned short* __restrict__ W, int ldw,
    float* __restrict__ C, int ldc,
    int K,
    const float* __restrict__ resid) {
  __shared__ __align__(16) unsigned short As[2][128 * 32];
  __shared__ __align__(16) unsigned short Ws[2][128 * 32];
  const int tid = threadIdx.x;
  const int bm = blockIdx.y * 128;
  const int bn = blockIdx.x * 128;
  const int lane = tid & 63;
  const int wv = tid >> 6;
  const int wm = (wv >> 1) * 64;
  const int wn = (wv & 1) * 64;
  const int fr = lane & 15;
  const int fs = lane >> 4;

  const int r0 = tid >> 2;
  const int s0 = (tid & 3) ^ (r0 & 3);

  const unsigned short* gA0 = A + (size_t)(bm + r0) * lda + s0 * 8;
  const unsigned short* gA1 = A + (size_t)(bm + r0 + 64) * lda + s0 * 8;
  const unsigned short* gW0 = W + (size_t)(bn + r0) * ldw + s0 * 8;
  const unsigned short* gW1 = W + (size_t)(bn + r0 + 64) * ldw + s0 * 8;

  f32x4 acc[4][4];
#pragma unroll
  for (int i = 0; i < 4; i++)
#pragma unroll
    for (int j = 0; j < 4; j++) acc[i][j] = (f32x4){0.f, 0.f, 0.f, 0.f};

  gl_lds16(gA0, &As[0][0] + tid * 8);
  gl_lds16(gA1, &As[0][2048] + tid * 8);
  gl_lds16(gW0, &Ws[0][0] + tid * 8);
  gl_lds16(gW1, &Ws[0][2048] + tid * 8);
  __syncthreads();

  const int nk = K >> 5;
  int buf = 0;
  for (int kk = 0; kk < nk; kk++) {
    if (kk + 1 < nk) {
      const int k0 = (kk + 1) * 32;
      gl_lds16(gA0 + k0, &As[buf ^ 1][0] + tid * 8);
      gl_lds16(gA1 + k0, &As[buf ^ 1][2048] + tid * 8);
      gl_lds16(gW0 + k0, &Ws[buf ^ 1][0] + tid * 8);
      gl_lds16(gW1 + k0, &Ws[buf ^ 1][2048] + tid * 8);
    }

    short8 af[4], bf[4];
#pragma unroll
    for (int i = 0; i < 4; i++) {
      int rowa = wm + i * 16 + fr;
      af[i] = *(const short8*)&As[buf][rowa * 32 + ((fs ^ (rowa & 3)) * 8)];
      int rowb = wn + i * 16 + fr;
      bf[i] = *(const short8*)&Ws[buf][rowb * 32 + ((fs ^ (rowb & 3)) * 8)];
    }
#pragma unroll
    for (int i = 0; i < 4; i++)
#pragma unroll
      for (int j = 0; j < 4; j++)
        acc[i][j] = __builtin_amdgcn_mfma_f32_16x16x32_bf16(af[i], bf[j], acc[i][j], 0, 0, 0);

    __syncthreads();
    buf ^= 1;
  }

#pragma unroll
  for (int i = 0; i < 4; i++) {
#pragma unroll
    for (int j = 0; j < 4; j++) {
#pragma unroll
      for (int r = 0; r < 4; r++) {
        int row = bm + wm + i * 16 + fs * 4 + r;
        int col = bn + wn + j * 16 + fr;
        float v = acc[i][j][r];
        if (EPI == 2) v += resid[(size_t)row * ldc + col];
        C[(size_t)row * ldc + col] = v;
      }
    }
  }
}

// ---------------------------------------------------------------------------
// 64x64-tile bf16 GEMM, global_load_lds + dbuf. EPI 1: softplus. EPI 2: +resid.
// ---------------------------------------------------------------------------
template<int EPI>
__global__ __launch_bounds__(256) void bt64_k(
    const unsigned short* __restrict__ A, int lda,
    const unsigned short* __restrict__ W, int ldw,
    float* __restrict__ C, int ldc,
    int K,
    const float* __restrict__ bias,
    const float* __restrict__ resid) {
  __shared__ __align__(16) unsigned short As[2][64 * 32];
  __shared__ __align__(16) unsigned short Ws[2][64 * 32];
  const int tid = threadIdx.x;
  const int bm = blockIdx.y * 64;
  const int bn = blockIdx.x * 64;
  const int lane = tid & 63;
  const int wv = tid >> 6;
  const int wm = (wv >> 1) * 32;
  const int wn = (wv & 1) * 32;
  const int fr = lane & 15;
  const int fs = lane >> 4;

  const int r0 = tid >> 2;
  const int s0 = (tid & 3) ^ (r0 & 3);

  const unsigned short* gA = A + (size_t)(bm + r0) * lda + s0 * 8;
  const unsigned short* gW = W + (size_t)(bn + r0) * ldw + s0 * 8;

  f32x4 acc[2][2];
#pragma unroll
  for (int i = 0; i < 2; i++)
#pragma unroll
    for (int j = 0; j < 2; j++) acc[i][j] = (f32x4){0.f, 0.f, 0.f, 0.f};

  gl_lds16(gA, &As[0][0] + tid * 8);
  gl_lds16(gW, &Ws[0][0] + tid * 8);
  __syncthreads();

  const int nk = K >> 5;
  int buf = 0;
  for (int kk = 0; kk < nk; kk++) {
    if (kk + 1 < nk) {
      const int k0 = (kk + 1) * 32;
      gl_lds16(gA + k0, &As[buf ^ 1][0] + tid * 8);
      gl_lds16(gW + k0, &Ws[buf ^ 1][0] + tid * 8);
    }

    short8 af[2], bf[2];
#pragma unroll
    for (int i = 0; i < 2; i++) {
      int rowa = wm + i * 16 + fr;
      af[i] = *(const short8*)&As[buf][rowa * 32 + ((fs ^ (rowa & 3)) * 8)];
      int rowb = wn + i * 16 + fr;
      bf[i] = *(const short8*)&Ws[buf][rowb * 32 + ((fs ^ (rowb & 3)) * 8)];
    }
#pragma unroll
    for (int i = 0; i < 2; i++)
#pragma unroll
      for (int j = 0; j < 2; j++)
        acc[i][j] = __builtin_amdgcn_mfma_f32_16x16x32_bf16(af[i], bf[j], acc[i][j], 0, 0, 0);

    __syncthreads();
    buf ^= 1;
  }

#pragma unroll
  for (int i = 0; i < 2; i++) {
#pragma unroll
    for (int j = 0; j < 2; j++) {
#pragma unroll
      for (int r = 0; r < 4; r++) {
        int row = bm + wm + i * 16 + fs * 4 + r;
        int col = bn + wn + j * 16 + fr;
        float v = acc[i][j][r];
        if (EPI == 1) {
          float xv = v + bias[col];
          v = (xv > 20.f) ? xv : log1pf(__expf(xv));
        }
        if (EPI == 2) v += resid[(size_t)row * ldc + col];
        C[(size_t)row * ldc + col] = v;
      }
    }
  }
}

// ---------------------------------------------------------------------------
// x_proj split-K, bf16
// ---------------------------------------------------------------------------
__global__ __launch_bounds__(256) void xp_k(
    const unsigned short* __restrict__ A,
    const unsigned short* __restrict__ W,
    float* __restrict__ part) {
  __shared__ __align__(16) unsigned short As[64][40];
  __shared__ __align__(16) unsigned short Ws[80][40];
  const int tid = threadIdx.x;
  const int ks = blockIdx.x;
  const int bm = blockIdx.y * 64;
  const int lane = tid & 63;
  const int wv = tid >> 6;
  const int fr = lane & 15;
  const int fs = lane >> 4;
  const int fk = fs * 8;

  const int ar = tid >> 2;
  const int ac = (tid & 3) * 8;
  const int k0base = ks * XKC;

  const unsigned short* gA  = A + (size_t)(bm + ar) * DI + k0base + ac;
  const unsigned short* gW0 = W + (size_t)ar * DI + k0base + ac;
  const unsigned short* gW1 = W + (size_t)(64 + ar) * DI + k0base + ac;

  f32x4 acc[5];
#pragma unroll
  for (int n = 0; n < 5; n++) acc[n] = (f32x4){0.f, 0.f, 0.f, 0.f};

  short8 aA, w0A, w1A;
  aA = *(const short8*)(gA);
  w0A = *(const short8*)(gW0);
  if (tid < 64) w1A = *(const short8*)(gW1);

  const int nk = XKC / 32;
  for (int kk = 0; kk < nk; kk++) {
    __syncthreads();
    *(short8*)&As[ar][ac] = aA;
    *(short8*)&Ws[ar][ac] = w0A;
    if (tid < 64) *(short8*)&Ws[64 + ar][ac] = w1A;
    __syncthreads();

    if (kk + 1 < nk) {
      const int k0 = (kk + 1) * 32;
      aA = *(const short8*)(gA + k0);
      w0A = *(const short8*)(gW0 + k0);
      if (tid < 64) w1A = *(const short8*)(gW1 + k0);
    }

    short8 af = *(const short8*)&As[wv * 16 + fr][fk];
#pragma unroll
    for (int n = 0; n < 5; n++) {
      short8 bf = *(const short8*)&Ws[n * 16 + fr][fk];
      acc[n] = __builtin_amdgcn_mfma_f32_16x16x32_bf16(af, bf, acc[n], 0, 0, 0);
    }
  }

#pragma unroll
  for (int n = 0; n < 5; n++) {
#pragma unroll
    for (int r = 0; r < 4; r++) {
      int row = bm + wv * 16 + fs * 4 + r;
      part[((size_t)ks * NTOK + row) * DBC + n * 16 + fr] = acc[n][r];
    }
  }
}

// sum XKS partials -> dbc (fp32) + bf16 zero-padded dt-input [m][64]
__global__ __launch_bounds__(256) void xp_reduce_k(const float* __restrict__ part,
                                                   float* __restrict__ dbc,
                                                   unsigned short* __restrict__ dtA) {
  int i = blockIdx.x * 256 + threadIdx.x;
  const f32x4* p4 = (const f32x4*)part;
  const int stride4 = NTOK * DBC / 4;
  f32x4 s = p4[i];
#pragma unroll
  for (int ks = 1; ks < XKS; ks++) {
    f32x4 v = p4[(size_t)ks * stride4 + i];
    s[0] += v[0]; s[1] += v[1]; s[2] += v[2]; s[3] += v[3];
  }
  ((f32x4*)dbc)[i] = s;
  int c4 = (i * 4) % DBC;
  int m = (i * 4) / DBC;
  if (c4 < 64) {
    union { ushort4v u4; __hip_bfloat162 h[2]; } u;
    if (c4 < NRANK) {
      float2 p;
      p.x = s[0]; p.y = s[1]; u.h[0] = __float22bfloat162_rn(p);
      p.x = s[2]; p.y = s[3]; u.h[1] = __float22bfloat162_rn(p);
    } else {
      u.u4 = (ushort4v){0, 0, 0, 0};
    }
    *(ushort4v*)&dtA[(size_t)m * 64 + c4] = u.u4;
  }
}

// depthwise causal conv(4) + bias + silu, register-carry
__global__ __launch_bounds__(256) void conv_silu_k(const float* __restrict__ xz,
                                                   const float* __restrict__ cw,
                                                   const float* __restrict__ cb,
                                                   float* __restrict__ xc,
                                                   unsigned short* __restrict__ xcb) {
  const int d = blockIdx.x * 256 + threadIdx.x;
  const int l0 = blockIdx.y * 16;
  const int b = blockIdx.z;
  const size_t mbase = (size_t)b * SEQ;
  const float w0 = cw[d * 4 + 0], w1 = cw[d * 4 + 1];
  const float w2 = cw[d * 4 + 2], w3 = cw[d * 4 + 3];
  const float bias = cb[d];
  float c3 = (l0 >= 3) ? xz[(mbase + l0 - 3) * (2 * DI) + d] : 0.f;
  float c2 = (l0 >= 2) ? xz[(mbase + l0 - 2) * (2 * DI) + d] : 0.f;
  float c1 = (l0 >= 1) ? xz[(mbase + l0 - 1) * (2 * DI) + d] : 0.f;
#pragma unroll
  for (int t = 0; t < 16; t++) {
    const int l = l0 + t;
    float cur = xz[(mbase + l) * (2 * DI) + d];
    float s = bias + w0 * c3 + w1 * c2 + w2 * c1 + w3 * cur;
    float sig = 1.f / (1.f + __expf(-s));
    float r = s * sig;
    size_t idx = (mbase + l) * DI + d;
    xc[idx] = r;
    xcb[idx] = f2bf(r);
    c3 = c2; c2 = c1; c1 = cur;
  }
}

// ---------------------------------------------------------------------------
// scan pass 1 (CHLEN=16): local h from 0, y_local, cumdt; chunk-end cumA/hloc.
// B/C staged in LDS; dt/xc preloaded to registers.
// ---------------------------------------------------------------------------
__global__ __launch_bounds__(256) void scan1_k(const float* __restrict__ dt,
                                               const float* __restrict__ xc,
                                               const float* __restrict__ dbc,
                                               const float* __restrict__ negA_l,
                                               float* __restrict__ cumA,
                                               float* __restrict__ hloc,
                                               float* __restrict__ yloc,
                                               float* __restrict__ cumdt) {
  __shared__ float Bs[CHLEN][DS];
  __shared__ float Cs[CHLEN][DS];
  const int tid = threadIdx.x;
  const int j = blockIdx.x;
  const int cg = blockIdx.y;
  const int b = cg / 6;
  const int d = (cg % 6) * 256 + tid;
  const int c = b * DI + d;
  const int m0 = b * SEQ + j * CHLEN;

  // stage B,C (16 rows x 32 cols)
#pragma unroll
  for (int e = tid; e < CHLEN * 32; e += 256) {
    int row = e >> 5, col = e & 31;
    float v = dbc[(size_t)(m0 + row) * DBC + NRANK + col];
    if (col < DS) Bs[row][col] = v; else Cs[row][col - DS] = v;
  }

  float Av[DS];
  const float* na = negA_l + (size_t)d * DS;
#pragma unroll
  for (int s = 0; s < DS; s++) Av[s] = na[s];
  const float Av0 = Av[0];
  bool fast = true;
#pragma unroll
  for (int s = 0; s < DS; s++)
    fast = fast && (fabsf(Av[s] - (s + 1) * Av0) <= 1e-4f * (s + 1));

  float dts[CHLEN], xcs[CHLEN];
#pragma unroll
  for (int t = 0; t < CHLEN; t++) {
    dts[t] = dt[(size_t)(m0 + t) * DI + d];
    xcs[t] = xc[(size_t)(m0 + t) * DI + d];
  }
  __syncthreads();

  float h[DS];
#pragma unroll
  for (int s = 0; s < DS; s++) h[s] = 0.f;
  float cd = 0.f;

  for (int t = 0; t < CHLEN; t++) {
    float dtv = dts[t];
    cd += dtv;
    float dtx = dtv * xcs[t];
    float ysum = 0.f;
    if (fast) {
      float e1 = __expf(dtv * Av0);
      float dA = e1;
      h[0] = fmaf(dA, h[0], dtx * Bs[t][0]);
      ysum = fmaf(h[0], Cs[t][0], ysum);
#pragma unroll
      for (int s = 1; s < DS; s++) {
        dA *= e1;
        h[s] = fmaf(dA, h[s], dtx * Bs[t][s]);
        ysum = fmaf(h[s], Cs[t][s], ysum);
      }
    } else {
#pragma unroll
      for (int s = 0; s < DS; s++) {
        float dA = __expf(dtv * Av[s]);
        h[s] = fmaf(dA, h[s], dtx * Bs[t][s]);
        ysum = fmaf(h[s], Cs[t][s], ysum);
      }
    }
    size_t mi = (size_t)(m0 + t) * DI + d;
    yloc[mi] = ysum;
    cumdt[mi] = cd;
  }

  size_t base = ((size_t)j * (BATCH * DI) + c) * DS;
#pragma unroll
  for (int s = 0; s < DS; s++) {
    cumA[base + s] = __expf(cd * Av[s]);
    hloc[base + s] = h[s];
  }
}

// pass 2: sequential chunk combine (64 chunks)
__global__ __launch_bounds__(256) void scan2_k(const float* __restrict__ cumA,
                                               const float* __restrict__ hloc,
                                               float* __restrict__ hin,
                                               float* __restrict__ states_out) {
  int idx = blockIdx.x * 256 + threadIdx.x;
  const int stride = BATCH * DI * DS;
  float h = 0.f;
  for (int j = 0; j < NCHUNK; j++) {
    hin[(size_t)j * stride + idx] = h;
    h = fmaf(cumA[(size_t)j * stride + idx], h, hloc[(size_t)j * stride + idx]);
  }
  states_out[idx] = h;
}

// pass 3: fully-parallel fixup: y = yloc + Sum_s C[s]*exp(cumdt*Av[s])*hin[s],
// then (y + D*xc)*silu(z) -> bf16
__global__ __launch_bounds__(256) void scanfix_k(const float* __restrict__ yloc,
                                                 const float* __restrict__ cumdt,
                                                 const float* __restrict__ xc,
                                                 const float* __restrict__ xz,
                                                 const float* __restrict__ dbc,
                                                 const float* __restrict__ negA_l,
                                                 const float* __restrict__ Dsk,
                                                 const float* __restrict__ hin,
                                                 unsigned short* __restrict__ y) {
  int idx = blockIdx.x * 256 + threadIdx.x;  // NTOK*DI
  int d = idx % DI;
  int m = idx / DI;
  int b = m / SEQ;
  int j = (m % SEQ) / CHLEN;
  float cd = cumdt[idx];
  float yv = yloc[idx];
  const float* na = negA_l + (size_t)d * DS;
  const float* cp = dbc + (size_t)m * DBC + NRANK + DS;
  size_t hbase = ((size_t)j * (BATCH * DI) + (size_t)b * DI + d) * DS;
  float corr = 0.f;
#pragma unroll
  for (int s = 0; s < DS; s++) {
    float P = __expf(cd * na[s]);
    corr = fmaf(P * hin[hbase + s], cp[s], corr);
  }
  yv += corr;
  float xv = xc[idx];
  float zv = xz[(size_t)m * (2 * DI) + DI + d];
  float sig = 1.f / (1.f + __expf(-zv));
  y[idx] = f2bf((yv + Dsk[d] * xv) * (zv * sig));
}

// LN (w,b) then optionally LN_noaffine + adaln modulate
template<bool ADA>
__global__ __launch_bounds__(256) void ln_k(const float* __restrict__ in,
                                            const float* __restrict__ w,
                                            const float* __restrict__ bb,
                                            const float* __restrict__ ss,
                                            float* __restrict__ out,
                                            unsigned short* __restrict__ outb) {
  __shared__ float red[8];
  const int row = blockIdx.x;
  const int bt = row / SEQ;
  const int tid = threadIdx.x;
  const float* x = in + (size_t)row * DM;
  float v[3];
#pragma unroll
  for (int i = 0; i < 3; i++) v[i] = x[tid + i * 256];
  float s1 = v[0] + v[1] + v[2];
  float s2 = v[0]*v[0] + v[1]*v[1] + v[2]*v[2];
#pragma unroll
  for (int o = 32; o > 0; o >>= 1) { s1 += __shfl_down(s1, o); s2 += __shfl_down(s2, o); }
  int wv = tid >> 6, ln = tid & 63;
  if (ln == 0) { red[wv*2] = s1; red[wv*2+1] = s2; }
  __syncthreads();
  s1 = red[0] + red[2] + red[4] + red[6];
  s2 = red[1] + red[3] + red[5] + red[7];
  float mu = s1 * (1.f / DM);
  float var = s2 * (1.f / DM) - mu * mu;
  float rs = rsqrtf(var + 1e-5f);
  float t[3];
#pragma unroll
  for (int i = 0; i < 3; i++) {
    int c = tid + i * 256;
    t[i] = (v[i] - mu) * rs * w[c] + bb[c];
  }
  if (!ADA) {
#pragma unroll
    for (int i = 0; i < 3; i++) out[(size_t)row * DM + tid + i * 256] = t[i];
    return;
  }
  __syncthreads();
  s1 = t[0] + t[1] + t[2];
  s2 = t[0]*t[0] + t[1]*t[1] + t[2]*t[2];
#pragma unroll
  for (int o = 32; o > 0; o >>= 1) { s1 += __shfl_down(s1, o); s2 += __shfl_down(s2, o); }
  if (ln == 0) { red[wv*2] = s1; red[wv*2+1] = s2; }
  __syncthreads();
  s1 = red[0] + red[2] + red[4] + red[6];
  s2 = red[1] + red[3] + red[5] + red[7];
  float mu2 = s1 * (1.f / DM);
  float var2 = s2 * (1.f / DM) - mu2 * mu2;
  float rs2 = rsqrtf(var2 + 1e-5f);
#pragma unroll
  for (int i = 0; i < 3; i++) {
    int c = tid + i * 256;
    float sc = ss[bt * (2 * DM) + c];
    float sh = ss[bt * (2 * DM) + DM + c];
    float r = (t[i] - mu2) * rs2 * (1.f + sc) + sh;
    out[(size_t)row * DM + c] = r;
    outb[(size_t)row * DM + c] = f2bf(r);
  }
}

// adaln precompute
__global__ __launch_bounds__(256) void adaln_pre_k(const float* __restrict__ cond,
                                                   const float* __restrict__ aw,
                                                   const float* __restrict__ ab,
                                                   float* __restrict__ ss) {
  int idx = blockIdx.x * 256 + threadIdx.x;
  int e = idx % (2 * DM);
  int b = (idx / (2 * DM)) % BATCH;
  int l = idx / (BATCH * 2 * DM);
  const float* c = cond + b * 128;
  const float* wp = aw + ((size_t)l * (2 * DM) + e) * 128;
  float s = ab[l * (2 * DM) + e];
  for (int k = 0; k < 128; k++) s = fmaf(c[k], wp[k], s);
  ss[idx] = s;
}

extern "C" void kernel_launch(void* const* d_in, const int* in_sizes, int n_in,
                              void* d_out, int out_size, void* d_ws, size_t ws_size,
                              hipStream_t stream) {
  const float* x      = (const float*)d_in[0];
  const float* cond   = (const float*)d_in[1];
  const float* in_w   = (const float*)d_in[2];
  const float* conv_w = (const float*)d_in[3];
  const float* conv_b = (const float*)d_in[4];
  const float* xp_w   = (const float*)d_in[5];
  const float* dtp_w  = (const float*)d_in[6];
  const float* dtp_b  = (const float*)d_in[7];
  const float* A_log  = (const float*)d_in[8];
  const float* Dsk    = (const float*)d_in[9];
  const float* out_w  = (const float*)d_in[10];
  const float* norm_w = (const float*)d_in[11];
  const float* norm_b = (const float*)d_in[12];
  const float* ada_w  = (const float*)d_in[13];
  const float* ada_b  = (const float*)d_in[14];
  const float* fn_w   = (const float*)d_in[15];
  const float* fn_b   = (const float*)d_in[16];

  float* out_h = (float*)d_out;
  float* out_states = out_h + (size_t)NTOK * DM;

  float* p = (float*)d_ws;
  float* h_cur = p; p += (size_t)NTOK * DM;
  float* xz    = p; p += (size_t)NTOK * 2 * DI;
  float* xc    = p; p += (size_t)NTOK * DI;
  float* dbc   = p; p += (size_t)NTOK * DBC;
  float* dtb   = p; p += (size_t)NTOK * DI;
  float* yb    = p; p += (size_t)NTOK * DI;
  float* res2  = p; p += (size_t)NTOK * DM;
  float* cumA  = p; p += (size_t)NCHUNK * BATCH * DI * DS;
  float* hloc  = p; p += (size_t)NCHUNK * BATCH * DI * DS;
  float* hin   = p; p += (size_t)NCHUNK * BATCH * DI * DS;
  float* ss    = p; p += (size_t)NL * BATCH * 2 * DM;
  float* xpart = p; p += (size_t)XKS * NTOK * DBC;
  float* yloc  = p; p += (size_t)NTOK * DI;
  float* cumdt = p; p += (size_t)NTOK * DI;
  float* negA  = p; p += (size_t)NL * DI * DS;
  unsigned short* q = (unsigned short*)p;
  unsigned short* in_w_bf  = q; q += (size_t)NL * 2 * DI * DM;
  unsigned short* out_w_bf = q; q += (size_t)NL * DM * DI;
  unsigned short* xp_w_bf  = q; q += (size_t)NL * DBC * DI;
  unsigned short* dtw_bf   = q; q += (size_t)NL * DI * 64;
  unsigned short* h_bf     = q; q += (size_t)NTOK * DM;
  unsigned short* xc_bf    = q; q += (size_t)NTOK * DI;
  unsigned short* dtA_bf   = q; q += (size_t)NTOK * 64;
  unsigned short* yb_bf    = (unsigned short*)yb;

  hipMemcpyAsync(h_cur, x, (size_t)NTOK * DM * sizeof(float),
                 hipMemcpyDeviceToDevice, stream);
  adaln_pre_k<<<72, 256, 0, stream>>>(cond, ada_w, ada_b, ss);
  f2b_k<<<1536, 256, 0, stream>>>(x, h_bf, NTOK * DM / 4);
  f2b_k<<<2048, 256, 0, stream>>>(in_w, in_w_bf, NL * 2 * DI * DM / 4);
  f2b_k<<<2048, 256, 0, stream>>>(out_w, out_w_bf, NL * DM * DI / 4);
  f2b_k<<<720, 256, 0, stream>>>(xp_w, xp_w_bf, NL * DBC * DI / 4);
  dtw_pad_k<<<(NL * 1536 * 64 + 255) / 256, 256, 0, stream>>>(dtp_w, dtw_bf);
  negA_k<<<(NL * DI * DS + 255) / 256, 256, 0, stream>>>(A_log, negA);

  for (int l = 0; l < NL; l++) {
    // in_proj
    bt128b_k<0><<<dim3(24, 16), 256, 0, stream>>>(
        h_bf, DM, in_w_bf + (size_t)l * 2 * DI * DM, DM, xz, 2 * DI,
        DM, nullptr);
    // conv + silu
    conv_silu_k<<<dim3(DI / 256, SEQ / 16, BATCH), 256, 0, stream>>>(
        xz, conv_w + (size_t)l * DI * 4, conv_b + (size_t)l * DI, xc, xc_bf);
    // x_proj split-K
    xp_k<<<dim3(XKS, NTOK / 64), 256, 0, stream>>>(
        xc_bf, xp_w_bf + (size_t)l * DBC * DI, xpart);
    xp_reduce_k<<<NTOK * DBC / 4 / 256, 256, 0, stream>>>(xpart, dbc, dtA_bf);
    // dt_proj + softplus
    bt64_k<1><<<dim3(DI / 64, NTOK / 64), 256, 0, stream>>>(
        dtA_bf, 64, dtw_bf + (size_t)l * DI * 64, 64, dtb, DI,
        64, dtp_b + (size_t)l * DI, nullptr);
    // chunked scan
    scan1_k<<<dim3(NCHUNK, 12), 256, 0, stream>>>(
        dtb, xc, dbc, negA + (size_t)l * DI * DS, cumA, hloc, yloc, cumdt);
    scan2_k<<<192, 256, 0, stream>>>(
        cumA, hloc, hin, out_states + (size_t)l * BATCH * DI * DS);
    scanfix_k<<<NTOK * DI / 256, 256, 0, stream>>>(
        yloc, cumdt, xc, xz, dbc, negA + (size_t)l * DI * DS,
        Dsk + (size_t)l * DI, hin, yb_bf);
    // out_proj + residual
    bt64_k<2><<<dim3(DM / 64, NTOK / 64), 256, 0, stream>>>(
        yb_bf, DI, out_w_bf + (size_t)l * DM * DI, DI, res2, DM,
        DI, nullptr, h_cur);
    // LN + adaln modulate
    ln_k<true><<<NTOK, 256, 0, stream>>>(
        res2, norm_w + (size_t)l * DM, norm_b + (size_t)l * DM,
        ss + (size_t)l * BATCH * 2 * DM, h_cur, h_bf);
  }
  ln_k<false><<<NTOK, 256, 0, stream>>>(h_cur, fn_w, fn_b, nullptr, out_h, nullptr);
}

// Round 7
// 865.284 us; speedup vs baseline: 1.7000x; 1.0565x over previous
//
#include <hip/hip_runtime.h>
#include <hip/hip_bf16.h>

#define NL 6
#define DM 768
#define DI 1536
#define DS 16
#define NRANK 48
#define DBC 80
#define BATCH 2
#define SEQ 1024
#define NTOK (BATCH*SEQ)
#define NCHUNK 64
#define CHLEN 16
#define XKS 8
#define XKC (DI/XKS)

typedef __attribute__((ext_vector_type(8))) short short8;
typedef __attribute__((ext_vector_type(4))) float f32x4;
typedef __attribute__((ext_vector_type(4))) unsigned short ushort4v;

__device__ inline unsigned short f2bf(float f) {
  union { float f; unsigned u; } x; x.f = f;
  unsigned r = x.u + 0x7FFF + ((x.u >> 16) & 1);
  return (unsigned short)(r >> 16);
}
__device__ inline float bf2f(unsigned short s) {
  union { unsigned u; float f; } x; x.u = ((unsigned)s) << 16;
  return x.f;
}

__device__ inline void gl_lds16(const unsigned short* g, unsigned short* l) {
  __builtin_amdgcn_global_load_lds(
      (const __attribute__((address_space(1))) unsigned int*)(g),
      (__attribute__((address_space(3))) unsigned int*)(l),
      16, 0, 0);
}

// spans (in f32x4 chunks)
#define SPAN_X   (NTOK * DM / 4)
#define SPAN_INW (NL * 2 * DI * DM / 4)
#define SPAN_OUW (NL * DM * DI / 4)
#define SPAN_XPW (NL * DBC * DI / 4)
#define SPAN_ALL (SPAN_X + SPAN_INW + SPAN_OUW + SPAN_XPW)

__device__ inline void cvt4_store(const float* s, unsigned short* d, int i) {
  f32x4 v = ((const f32x4*)s)[i];
  union { ushort4v u4; __hip_bfloat162 h[2]; } u;
  float2 p;
  p.x = v[0]; p.y = v[1]; u.h[0] = __float22bfloat162_rn(p);
  p.x = v[2]; p.y = v[3]; u.h[1] = __float22bfloat162_rn(p);
  ((ushort4v*)d)[i] = u.u4;
}

// one kernel: convert x, in_w, out_w, xp_w to bf16
__global__ __launch_bounds__(256) void cvtall_k(const float* __restrict__ x,
                                                const float* __restrict__ inw,
                                                const float* __restrict__ ouw,
                                                const float* __restrict__ xpw,
                                                unsigned short* __restrict__ xb,
                                                unsigned short* __restrict__ inwb,
                                                unsigned short* __restrict__ ouwb,
                                                unsigned short* __restrict__ xpwb) {
  for (int i = blockIdx.x * 256 + threadIdx.x; i < SPAN_ALL; i += gridDim.x * 256) {
    if (i < SPAN_X) cvt4_store(x, xb, i);
    else if (i < SPAN_X + SPAN_INW) cvt4_store(inw, inwb, i - SPAN_X);
    else if (i < SPAN_X + SPAN_INW + SPAN_OUW) cvt4_store(ouw, ouwb, i - SPAN_X - SPAN_INW);
    else cvt4_store(xpw, xpwb, i - SPAN_X - SPAN_INW - SPAN_OUW);
  }
}

// misc: dtp_w pad->bf16 [NL][1536][64] + negA = -exp(A_log)
__global__ __launch_bounds__(256) void misc_pre_k(const float* __restrict__ w,
                                                  const float* __restrict__ al,
                                                  unsigned short* __restrict__ wb,
                                                  float* __restrict__ na) {
  int idx = blockIdx.x * 256 + threadIdx.x;
  const int NDT = NL * 1536 * 64;
  if (idx < NDT) {
    int col = idx & 63;
    int row = idx >> 6;
    wb[idx] = (col < NRANK) ? f2bf(w[(size_t)row * NRANK + col]) : (unsigned short)0;
  } else if (idx < NDT + NL * DI * DS) {
    int k = idx - NDT;
    na[k] = -__expf(al[k]);
  }
}

// ---------------------------------------------------------------------------
// 128x128-tile bf16 GEMM -> bf16 output (in_proj). gl_lds + double buffer.
// ---------------------------------------------------------------------------
__global__ __launch_bounds__(256) void bt128b_k(
    const unsigned short* __restrict__ A, int lda,
    const unsigned short* __restrict__ W, int ldw,
    unsigned short* __restrict__ C, int ldc,
    int K) {
  __shared__ __align__(16) unsigned short As[2][128 * 32];
  __shared__ __align__(16) unsigned short Ws[2][128 * 32];
  const int tid = threadIdx.x;
  const int bm = blockIdx.y * 128;
  const int bn = blockIdx.x * 128;
  const int lane = tid & 63;
  const int wv = tid >> 6;
  const int wm = (wv >> 1) * 64;
  const int wn = (wv & 1) * 64;
  const int fr = lane & 15;
  const int fs = lane >> 4;

  const int r0 = tid >> 2;
  const int s0 = (tid & 3) ^ (r0 & 3);

  const unsigned short* gA0 = A + (size_t)(bm + r0) * lda + s0 * 8;
  const unsigned short* gA1 = A + (size_t)(bm + r0 + 64) * lda + s0 * 8;
  const unsigned short* gW0 = W + (size_t)(bn + r0) * ldw + s0 * 8;
  const unsigned short* gW1 = W + (size_t)(bn + r0 + 64) * ldw + s0 * 8;

  f32x4 acc[4][4];
#pragma unroll
  for (int i = 0; i < 4; i++)
#pragma unroll
    for (int j = 0; j < 4; j++) acc[i][j] = (f32x4){0.f, 0.f, 0.f, 0.f};

  gl_lds16(gA0, &As[0][0] + tid * 8);
  gl_lds16(gA1, &As[0][2048] + tid * 8);
  gl_lds16(gW0, &Ws[0][0] + tid * 8);
  gl_lds16(gW1, &Ws[0][2048] + tid * 8);
  __syncthreads();

  const int nk = K >> 5;
  int buf = 0;
  for (int kk = 0; kk < nk; kk++) {
    if (kk + 1 < nk) {
      const int k0 = (kk + 1) * 32;
      gl_lds16(gA0 + k0, &As[buf ^ 1][0] + tid * 8);
      gl_lds16(gA1 + k0, &As[buf ^ 1][2048] + tid * 8);
      gl_lds16(gW0 + k0, &Ws[buf ^ 1][0] + tid * 8);
      gl_lds16(gW1 + k0, &Ws[buf ^ 1][2048] + tid * 8);
    }

    short8 af[4], bf[4];
#pragma unroll
    for (int i = 0; i < 4; i++) {
      int rowa = wm + i * 16 + fr;
      af[i] = *(const short8*)&As[buf][rowa * 32 + ((fs ^ (rowa & 3)) * 8)];
      int rowb = wn + i * 16 + fr;
      bf[i] = *(const short8*)&Ws[buf][rowb * 32 + ((fs ^ (rowb & 3)) * 8)];
    }
#pragma unroll
    for (int i = 0; i < 4; i++)
#pragma unroll
      for (int j = 0; j < 4; j++)
        acc[i][j] = __builtin_amdgcn_mfma_f32_16x16x32_bf16(af[i], bf[j], acc[i][j], 0, 0, 0);

    __syncthreads();
    buf ^= 1;
  }

#pragma unroll
  for (int i = 0; i < 4; i++) {
#pragma unroll
    for (int j = 0; j < 4; j++) {
#pragma unroll
      for (int r = 0; r < 4; r++) {
        int row = bm + wm + i * 16 + fs * 4 + r;
        int col = bn + wn + j * 16 + fr;
        C[(size_t)row * ldc + col] = f2bf(acc[i][j][r]);
      }
    }
  }
}

// ---------------------------------------------------------------------------
// 64x64-tile bf16 GEMM. EPI 1: softplus(v+bias)->bf16. EPI 2: fp32 v+resid.
// ---------------------------------------------------------------------------
template<int EPI>
__global__ __launch_bounds__(256) void bt64_k(
    const unsigned short* __restrict__ A, int lda,
    const unsigned short* __restrict__ W, int ldw,
    void* __restrict__ Cv, int ldc,
    int K,
    const float* __restrict__ bias,
    const float* __restrict__ resid) {
  __shared__ __align__(16) unsigned short As[2][64 * 32];
  __shared__ __align__(16) unsigned short Ws[2][64 * 32];
  const int tid = threadIdx.x;
  const int bm = blockIdx.y * 64;
  const int bn = blockIdx.x * 64;
  const int lane = tid & 63;
  const int wv = tid >> 6;
  const int wm = (wv >> 1) * 32;
  const int wn = (wv & 1) * 32;
  const int fr = lane & 15;
  const int fs = lane >> 4;

  const int r0 = tid >> 2;
  const int s0 = (tid & 3) ^ (r0 & 3);

  const unsigned short* gA = A + (size_t)(bm + r0) * lda + s0 * 8;
  const unsigned short* gW = W + (size_t)(bn + r0) * ldw + s0 * 8;

  f32x4 acc[2][2];
#pragma unroll
  for (int i = 0; i < 2; i++)
#pragma unroll
    for (int j = 0; j < 2; j++) acc[i][j] = (f32x4){0.f, 0.f, 0.f, 0.f};

  gl_lds16(gA, &As[0][0] + tid * 8);
  gl_lds16(gW, &Ws[0][0] + tid * 8);
  __syncthreads();

  const int nk = K >> 5;
  int buf = 0;
  for (int kk = 0; kk < nk; kk++) {
    if (kk + 1 < nk) {
      const int k0 = (kk + 1) * 32;
      gl_lds16(gA + k0, &As[buf ^ 1][0] + tid * 8);
      gl_lds16(gW + k0, &Ws[buf ^ 1][0] + tid * 8);
    }

    short8 af[2], bf[2];
#pragma unroll
    for (int i = 0; i < 2; i++) {
      int rowa = wm + i * 16 + fr;
      af[i] = *(const short8*)&As[buf][rowa * 32 + ((fs ^ (rowa & 3)) * 8)];
      int rowb = wn + i * 16 + fr;
      bf[i] = *(const short8*)&Ws[buf][rowb * 32 + ((fs ^ (rowb & 3)) * 8)];
    }
#pragma unroll
    for (int i = 0; i < 2; i++)
#pragma unroll
      for (int j = 0; j < 2; j++)
        acc[i][j] = __builtin_amdgcn_mfma_f32_16x16x32_bf16(af[i], bf[j], acc[i][j], 0, 0, 0);

    __syncthreads();
    buf ^= 1;
  }

#pragma unroll
  for (int i = 0; i < 2; i++) {
#pragma unroll
    for (int j = 0; j < 2; j++) {
#pragma unroll
      for (int r = 0; r < 4; r++) {
        int row = bm + wm + i * 16 + fs * 4 + r;
        int col = bn + wn + j * 16 + fr;
        float v = acc[i][j][r];
        if (EPI == 1) {
          float xv = v + bias[col];
          float sp = (xv > 20.f) ? xv : log1pf(__expf(xv));
          ((unsigned short*)Cv)[(size_t)row * ldc + col] = f2bf(sp);
        }
        if (EPI == 2) {
          ((float*)Cv)[(size_t)row * ldc + col] = v + resid[(size_t)row * ldc + col];
        }
      }
    }
  }
}

// ---------------------------------------------------------------------------
// x_proj split-K, bf16
// ---------------------------------------------------------------------------
__global__ __launch_bounds__(256) void xp_k(
    const unsigned short* __restrict__ A,
    const unsigned short* __restrict__ W,
    float* __restrict__ part) {
  __shared__ __align__(16) unsigned short As[64][40];
  __shared__ __align__(16) unsigned short Ws[80][40];
  const int tid = threadIdx.x;
  const int ks = blockIdx.x;
  const int bm = blockIdx.y * 64;
  const int lane = tid & 63;
  const int wv = tid >> 6;
  const int fr = lane & 15;
  const int fs = lane >> 4;
  const int fk = fs * 8;

  const int ar = tid >> 2;
  const int ac = (tid & 3) * 8;
  const int k0base = ks * XKC;

  const unsigned short* gA  = A + (size_t)(bm + ar) * DI + k0base + ac;
  const unsigned short* gW0 = W + (size_t)ar * DI + k0base + ac;
  const unsigned short* gW1 = W + (size_t)(64 + ar) * DI + k0base + ac;

  f32x4 acc[5];
#pragma unroll
  for (int n = 0; n < 5; n++) acc[n] = (f32x4){0.f, 0.f, 0.f, 0.f};

  short8 aA, w0A, w1A;
  aA = *(const short8*)(gA);
  w0A = *(const short8*)(gW0);
  if (tid < 64) w1A = *(const short8*)(gW1);

  const int nk = XKC / 32;
  for (int kk = 0; kk < nk; kk++) {
    __syncthreads();
    *(short8*)&As[ar][ac] = aA;
    *(short8*)&Ws[ar][ac] = w0A;
    if (tid < 64) *(short8*)&Ws[64 + ar][ac] = w1A;
    __syncthreads();

    if (kk + 1 < nk) {
      const int k0 = (kk + 1) * 32;
      aA = *(const short8*)(gA + k0);
      w0A = *(const short8*)(gW0 + k0);
      if (tid < 64) w1A = *(const short8*)(gW1 + k0);
    }

    short8 af = *(const short8*)&As[wv * 16 + fr][fk];
#pragma unroll
    for (int n = 0; n < 5; n++) {
      short8 bf = *(const short8*)&Ws[n * 16 + fr][fk];
      acc[n] = __builtin_amdgcn_mfma_f32_16x16x32_bf16(af, bf, acc[n], 0, 0, 0);
    }
  }

#pragma unroll
  for (int n = 0; n < 5; n++) {
#pragma unroll
    for (int r = 0; r < 4; r++) {
      int row = bm + wv * 16 + fs * 4 + r;
      part[((size_t)ks * NTOK + row) * DBC + n * 16 + fr] = acc[n][r];
    }
  }
}

// sum XKS partials -> dbc (fp32) + bf16 zero-padded dt-input [m][64]
__global__ __launch_bounds__(256) void xp_reduce_k(const float* __restrict__ part,
                                                   float* __restrict__ dbc,
                                                   unsigned short* __restrict__ dtA) {
  int i = blockIdx.x * 256 + threadIdx.x;
  const f32x4* p4 = (const f32x4*)part;
  const int stride4 = NTOK * DBC / 4;
  f32x4 s = p4[i];
#pragma unroll
  for (int ks = 1; ks < XKS; ks++) {
    f32x4 v = p4[(size_t)ks * stride4 + i];
    s[0] += v[0]; s[1] += v[1]; s[2] += v[2]; s[3] += v[3];
  }
  ((f32x4*)dbc)[i] = s;
  int c4 = (i * 4) % DBC;
  int m = (i * 4) / DBC;
  if (c4 < 64) {
    union { ushort4v u4; __hip_bfloat162 h[2]; } u;
    if (c4 < NRANK) {
      float2 p;
      p.x = s[0]; p.y = s[1]; u.h[0] = __float22bfloat162_rn(p);
      p.x = s[2]; p.y = s[3]; u.h[1] = __float22bfloat162_rn(p);
    } else {
      u.u4 = (ushort4v){0, 0, 0, 0};
    }
    *(ushort4v*)&dtA[(size_t)m * 64 + c4] = u.u4;
  }
}

// depthwise causal conv(4) + bias + silu, register-carry; bf16 in/out
__global__ __launch_bounds__(256) void conv_silu_k(const unsigned short* __restrict__ xz,
                                                   const float* __restrict__ cw,
                                                   const float* __restrict__ cb,
                                                   unsigned short* __restrict__ xcb) {
  const int d = blockIdx.x * 256 + threadIdx.x;
  const int l0 = blockIdx.y * 16;
  const int b = blockIdx.z;
  const size_t mbase = (size_t)b * SEQ;
  const float w0 = cw[d * 4 + 0], w1 = cw[d * 4 + 1];
  const float w2 = cw[d * 4 + 2], w3 = cw[d * 4 + 3];
  const float bias = cb[d];
  float c3 = (l0 >= 3) ? bf2f(xz[(mbase + l0 - 3) * (2 * DI) + d]) : 0.f;
  float c2 = (l0 >= 2) ? bf2f(xz[(mbase + l0 - 2) * (2 * DI) + d]) : 0.f;
  float c1 = (l0 >= 1) ? bf2f(xz[(mbase + l0 - 1) * (2 * DI) + d]) : 0.f;
#pragma unroll
  for (int t = 0; t < 16; t++) {
    const int l = l0 + t;
    float cur = bf2f(xz[(mbase + l) * (2 * DI) + d]);
    float s = bias + w0 * c3 + w1 * c2 + w2 * c1 + w3 * cur;
    float sig = 1.f / (1.f + __expf(-s));
    xcb[(mbase + l) * DI + d] = f2bf(s * sig);
    c3 = c2; c2 = c1; c1 = cur;
  }
}

// ---------------------------------------------------------------------------
// scan pass 1 (CHLEN=16): bf16 dt/xc in, bf16 yloc out, cumdt fp32.
// ---------------------------------------------------------------------------
__global__ __launch_bounds__(256) void scan1_k(const unsigned short* __restrict__ dt,
                                               const unsigned short* __restrict__ xc,
                                               const float* __restrict__ dbc,
                                               const float* __restrict__ negA_l,
                                               float* __restrict__ cumA,
                                               float* __restrict__ hloc,
                                               unsigned short* __restrict__ yloc,
                                               float* __restrict__ cumdt) {
  __shared__ float Bs[CHLEN][DS];
  __shared__ float Cs[CHLEN][DS];
  const int tid = threadIdx.x;
  const int j = blockIdx.x;
  const int cg = blockIdx.y;
  const int b = cg / 6;
  const int d = (cg % 6) * 256 + tid;
  const int c = b * DI + d;
  const int m0 = b * SEQ + j * CHLEN;

#pragma unroll
  for (int e = tid; e < CHLEN * 32; e += 256) {
    int row = e >> 5, col = e & 31;
    float v = dbc[(size_t)(m0 + row) * DBC + NRANK + col];
    if (col < DS) Bs[row][col] = v; else Cs[row][col - DS] = v;
  }

  float Av[DS];
  const float* na = negA_l + (size_t)d * DS;
#pragma unroll
  for (int s = 0; s < DS; s++) Av[s] = na[s];
  const float Av0 = Av[0];
  bool fast = true;
#pragma unroll
  for (int s = 0; s < DS; s++)
    fast = fast && (fabsf(Av[s] - (s + 1) * Av0) <= 1e-4f * (s + 1));

  float dts[CHLEN], xcs[CHLEN];
#pragma unroll
  for (int t = 0; t < CHLEN; t++) {
    dts[t] = bf2f(dt[(size_t)(m0 + t) * DI + d]);
    xcs[t] = bf2f(xc[(size_t)(m0 + t) * DI + d]);
  }
  __syncthreads();

  float h[DS];
#pragma unroll
  for (int s = 0; s < DS; s++) h[s] = 0.f;
  float cd = 0.f;

  for (int t = 0; t < CHLEN; t++) {
    float dtv = dts[t];
    cd += dtv;
    float dtx = dtv * xcs[t];
    float ysum = 0.f;
    if (fast) {
      float e1 = __expf(dtv * Av0);
      float dA = e1;
      h[0] = fmaf(dA, h[0], dtx * Bs[t][0]);
      ysum = fmaf(h[0], Cs[t][0], ysum);
#pragma unroll
      for (int s = 1; s < DS; s++) {
        dA *= e1;
        h[s] = fmaf(dA, h[s], dtx * Bs[t][s]);
        ysum = fmaf(h[s], Cs[t][s], ysum);
      }
    } else {
#pragma unroll
      for (int s = 0; s < DS; s++) {
        float dA = __expf(dtv * Av[s]);
        h[s] = fmaf(dA, h[s], dtx * Bs[t][s]);
        ysum = fmaf(h[s], Cs[t][s], ysum);
      }
    }
    size_t mi = (size_t)(m0 + t) * DI + d;
    yloc[mi] = f2bf(ysum);
    cumdt[mi] = cd;
  }

  size_t base = ((size_t)j * (BATCH * DI) + c) * DS;
#pragma unroll
  for (int s = 0; s < DS; s++) {
    cumA[base + s] = __expf(cd * Av[s]);
    hloc[base + s] = h[s];
  }
}

// pass 2: sequential chunk combine
__global__ __launch_bounds__(256) void scan2_k(const float* __restrict__ cumA,
                                               const float* __restrict__ hloc,
                                               float* __restrict__ hin,
                                               float* __restrict__ states_out) {
  int idx = blockIdx.x * 256 + threadIdx.x;
  const int stride = BATCH * DI * DS;
  float h = 0.f;
  for (int j = 0; j < NCHUNK; j++) {
    hin[(size_t)j * stride + idx] = h;
    h = fmaf(cumA[(size_t)j * stride + idx], h, hloc[(size_t)j * stride + idx]);
  }
  states_out[idx] = h;
}

// pass 3: parallel fixup, vectorized
__global__ __launch_bounds__(256) void scanfix_k(const unsigned short* __restrict__ yloc,
                                                 const float* __restrict__ cumdt,
                                                 const unsigned short* __restrict__ xc,
                                                 const unsigned short* __restrict__ xz,
                                                 const float* __restrict__ dbc,
                                                 const float* __restrict__ negA_l,
                                                 const float* __restrict__ Dsk,
                                                 const float* __restrict__ hin,
                                                 unsigned short* __restrict__ y) {
  int idx = blockIdx.x * 256 + threadIdx.x;
  int d = idx % DI;
  int m = idx / DI;
  int b = m / SEQ;
  int j = (m % SEQ) / CHLEN;
  float cd = cumdt[idx];
  float yv = bf2f(yloc[idx]);
  const f32x4* na4 = (const f32x4*)(negA_l + (size_t)d * DS);
  const f32x4* cp4 = (const f32x4*)(dbc + (size_t)m * DBC + NRANK + DS);
  const f32x4* h4  = (const f32x4*)(hin + ((size_t)j * (BATCH * DI) + (size_t)b * DI + d) * DS);
  float corr = 0.f;
#pragma unroll
  for (int q = 0; q < 4; q++) {
    f32x4 na = na4[q], cp = cp4[q], hh = h4[q];
#pragma unroll
    for (int e = 0; e < 4; e++)
      corr = fmaf(__expf(cd * na[e]) * hh[e], cp[e], corr);
  }
  yv += corr;
  float xv = bf2f(xc[idx]);
  float zv = bf2f(xz[(size_t)m * (2 * DI) + DI + d]);
  float sig = 1.f / (1.f + __expf(-zv));
  y[idx] = f2bf((yv + Dsk[d] * xv) * (zv * sig));
}

// LN (w,b) then optionally LN_noaffine + adaln modulate
template<bool ADA>
__global__ __launch_bounds__(256) void ln_k(const float* __restrict__ in,
                                            const float* __restrict__ w,
                                            const float* __restrict__ bb,
                                            const float* __restrict__ ss,
                                            float* __restrict__ out,
                                            unsigned short* __restrict__ outb) {
  __shared__ float red[8];
  const int row = blockIdx.x;
  const int bt = row / SEQ;
  const int tid = threadIdx.x;
  const float* x = in + (size_t)row * DM;
  float v[3];
#pragma unroll
  for (int i = 0; i < 3; i++) v[i] = x[tid + i * 256];
  float s1 = v[0] + v[1] + v[2];
  float s2 = v[0]*v[0] + v[1]*v[1] + v[2]*v[2];
#pragma unroll
  for (int o = 32; o > 0; o >>= 1) { s1 += __shfl_down(s1, o); s2 += __shfl_down(s2, o); }
  int wv = tid >> 6, ln = tid & 63;
  if (ln == 0) { red[wv*2] = s1; red[wv*2+1] = s2; }
  __syncthreads();
  s1 = red[0] + red[2] + red[4] + red[6];
  s2 = red[1] + red[3] + red[5] + red[7];
  float mu = s1 * (1.f / DM);
  float var = s2 * (1.f / DM) - mu * mu;
  float rs = rsqrtf(var + 1e-5f);
  float t[3];
#pragma unroll
  for (int i = 0; i < 3; i++) {
    int c = tid + i * 256;
    t[i] = (v[i] - mu) * rs * w[c] + bb[c];
  }
  if (!ADA) {
#pragma unroll
    for (int i = 0; i < 3; i++) out[(size_t)row * DM + tid + i * 256] = t[i];
    return;
  }
  __syncthreads();
  s1 = t[0] + t[1] + t[2];
  s2 = t[0]*t[0] + t[1]*t[1] + t[2]*t[2];
#pragma unroll
  for (int o = 32; o > 0; o >>= 1) { s1 += __shfl_down(s1, o); s2 += __shfl_down(s2, o); }
  if (ln == 0) { red[wv*2] = s1; red[wv*2+1] = s2; }
  __syncthreads();
  s1 = red[0] + red[2] + red[4] + red[6];
  s2 = red[1] + red[3] + red[5] + red[7];
  float mu2 = s1 * (1.f / DM);
  float var2 = s2 * (1.f / DM) - mu2 * mu2;
  float rs2 = rsqrtf(var2 + 1e-5f);
#pragma unroll
  for (int i = 0; i < 3; i++) {
    int c = tid + i * 256;
    float sc = ss[bt * (2 * DM) + c];
    float sh = ss[bt * (2 * DM) + DM + c];
    float r = (t[i] - mu2) * rs2 * (1.f + sc) + sh;
    out[(size_t)row * DM + c] = r;
    outb[(size_t)row * DM + c] = f2bf(r);
  }
}

// adaln precompute
__global__ __launch_bounds__(256) void adaln_pre_k(const float* __restrict__ cond,
                                                   const float* __restrict__ aw,
                                                   const float* __restrict__ ab,
                                                   float* __restrict__ ss) {
  int idx = blockIdx.x * 256 + threadIdx.x;
  int e = idx % (2 * DM);
  int b = (idx / (2 * DM)) % BATCH;
  int l = idx / (BATCH * 2 * DM);
  const float* c = cond + b * 128;
  const float* wp = aw + ((size_t)l * (2 * DM) + e) * 128;
  float s = ab[l * (2 * DM) + e];
  for (int k = 0; k < 128; k++) s = fmaf(c[k], wp[k], s);
  ss[idx] = s;
}

extern "C" void kernel_launch(void* const* d_in, const int* in_sizes, int n_in,
                              void* d_out, int out_size, void* d_ws, size_t ws_size,
                              hipStream_t stream) {
  const float* x      = (const float*)d_in[0];
  const float* cond   = (const float*)d_in[1];
  const float* in_w   = (const float*)d_in[2];
  const float* conv_w = (const float*)d_in[3];
  const float* conv_b = (const float*)d_in[4];
  const float* xp_w   = (const float*)d_in[5];
  const float* dtp_w  = (const float*)d_in[6];
  const float* dtp_b  = (const float*)d_in[7];
  const float* A_log  = (const float*)d_in[8];
  const float* Dsk    = (const float*)d_in[9];
  const float* out_w  = (const float*)d_in[10];
  const float* norm_w = (const float*)d_in[11];
  const float* norm_b = (const float*)d_in[12];
  const float* ada_w  = (const float*)d_in[13];
  const float* ada_b  = (const float*)d_in[14];
  const float* fn_w   = (const float*)d_in[15];
  const float* fn_b   = (const float*)d_in[16];

  float* out_h = (float*)d_out;
  float* out_states = out_h + (size_t)NTOK * DM;

  float* p = (float*)d_ws;
  float* h_cur = p; p += (size_t)NTOK * DM;
  float* dbc   = p; p += (size_t)NTOK * DBC;
  float* res2  = p; p += (size_t)NTOK * DM;
  float* cumA  = p; p += (size_t)NCHUNK * BATCH * DI * DS;
  float* hloc  = p; p += (size_t)NCHUNK * BATCH * DI * DS;
  float* hin   = p; p += (size_t)NCHUNK * BATCH * DI * DS;
  float* ss    = p; p += (size_t)NL * BATCH * 2 * DM;
  float* xpart = p; p += (size_t)XKS * NTOK * DBC;
  float* cumdt = p; p += (size_t)NTOK * DI;
  float* negA  = p; p += (size_t)NL * DI * DS;
  unsigned short* q = (unsigned short*)p;
  unsigned short* in_w_bf  = q; q += (size_t)NL * 2 * DI * DM;
  unsigned short* out_w_bf = q; q += (size_t)NL * DM * DI;
  unsigned short* xp_w_bf  = q; q += (size_t)NL * DBC * DI;
  unsigned short* dtw_bf   = q; q += (size_t)NL * DI * 64;
  unsigned short* h_bf     = q; q += (size_t)NTOK * DM;
  unsigned short* xz_bf    = q; q += (size_t)NTOK * 2 * DI;
  unsigned short* xc_bf    = q; q += (size_t)NTOK * DI;
  unsigned short* dtb_bf   = q; q += (size_t)NTOK * DI;
  unsigned short* yloc_bf  = q; q += (size_t)NTOK * DI;
  unsigned short* yb_bf    = q; q += (size_t)NTOK * DI;
  unsigned short* dtA_bf   = q; q += (size_t)NTOK * 64;

  hipMemcpyAsync(h_cur, x, (size_t)NTOK * DM * sizeof(float),
                 hipMemcpyDeviceToDevice, stream);
  adaln_pre_k<<<72, 256, 0, stream>>>(cond, ada_w, ada_b, ss);
  cvtall_k<<<2048, 256, 0, stream>>>(x, in_w, out_w, xp_w,
                                     h_bf, in_w_bf, out_w_bf, xp_w_bf);
  misc_pre_k<<<(NL * 1536 * 64 + NL * DI * DS + 255) / 256, 256, 0, stream>>>(
      dtp_w, A_log, dtw_bf, negA);

  for (int l = 0; l < NL; l++) {
    // in_proj -> xz (bf16)
    bt128b_k<<<dim3(24, 16), 256, 0, stream>>>(
        h_bf, DM, in_w_bf + (size_t)l * 2 * DI * DM, DM, xz_bf, 2 * DI, DM);
    // conv + silu -> xc (bf16)
    conv_silu_k<<<dim3(DI / 256, SEQ / 16, BATCH), 256, 0, stream>>>(
        xz_bf, conv_w + (size_t)l * DI * 4, conv_b + (size_t)l * DI, xc_bf);
    // x_proj split-K
    xp_k<<<dim3(XKS, NTOK / 64), 256, 0, stream>>>(
        xc_bf, xp_w_bf + (size_t)l * DBC * DI, xpart);
    xp_reduce_k<<<NTOK * DBC / 4 / 256, 256, 0, stream>>>(xpart, dbc, dtA_bf);
    // dt_proj + softplus -> dtb (bf16)
    bt64_k<1><<<dim3(DI / 64, NTOK / 64), 256, 0, stream>>>(
        dtA_bf, 64, dtw_bf + (size_t)l * DI * 64, 64, dtb_bf, DI,
        64, dtp_b + (size_t)l * DI, nullptr);
    // chunked scan
    scan1_k<<<dim3(NCHUNK, 12), 256, 0, stream>>>(
        dtb_bf, xc_bf, dbc, negA + (size_t)l * DI * DS, cumA, hloc,
        yloc_bf, cumdt);
    scan2_k<<<192, 256, 0, stream>>>(
        cumA, hloc, hin, out_states + (size_t)l * BATCH * DI * DS);
    scanfix_k<<<NTOK * DI / 256, 256, 0, stream>>>(
        yloc_bf, cumdt, xc_bf, xz_bf, dbc, negA + (size_t)l * DI * DS,
        Dsk + (size_t)l * DI, hin, yb_bf);
    // out_proj + residual
    bt64_k<2><<<dim3(DM / 64, NTOK / 64), 256, 0, stream>>>(
        yb_bf, DI, out_w_bf + (size_t)l * DM * DI, DI, res2, DM,
        DI, nullptr, h_cur);
    // LN + adaln modulate
    ln_k<true><<<NTOK, 256, 0, stream>>>(
        res2, norm_w + (size_t)l * DM, norm_b + (size_t)l * DM,
        ss + (size_t)l * BATCH * 2 * DM, h_cur, h_bf);
  }
  ln_k<false><<<NTOK, 256, 0, stream>>>(h_cur, fn_w, fn_b, nullptr, out_h, nullptr);
}